// Round 14
// baseline (405.823 us; speedup 1.0000x reference)
//
#include <hip/hip_runtime.h>

#define PN 10000
#define UN 8000
#define BN 4096
#define NGE 320000
#define NDE 320000
#define NUE 400000
#define NPUE 400000
// bf16 inputs pre-scaled by sqrt(5*log2(e)) so infonce epilogue is a bare exp2
#define SCALE_BF 2.6857914f
// cumulative edge offsets: geo, tar, src, up, pu
#define E0 320000
#define E1 640000
#define E2 960000
#define E3 1360000
#define E4 1760000

// bucketed scatter: chunks of 4096 edges, per-matrix chunk counts
#define SCHUNK 4096
#define NC_A 79     // ceil(320000/4096) geo
#define NC_B 158    // + tar
#define NC_C 237    // + src
#define NC_D 335    // + up (98 chunks)
#define NCT 433     // + pu (98 chunks)
// 128 row-buckets per matrix; RPB = rows per bucket
#define RPB_P 79    // 128*79 = 10112 >= 10000
#define RPB_U 63    // 128*63 = 8064  >= 8000
// magic for exact div: b = (row*MAGIC)>>22
#define MAGIC_P 53093u   // ceil(2^22/79)
#define MAGIC_U 66577u   // ceil(2^22/63)

// LDS-partial histogram: 32 blocks per P-matrix, 40 per U-matrix, 10000 edges each
#define HW_P 32
#define HW_U 40
// partial array offsets (ints)
#define PT_GEO 0
#define PT_TAR 320000
#define PT_SRC 640000
#define PT_UP  960000
#define PT_PU  1280000

#define NSTR 79    // infonce stripes per dim

typedef __attribute__((ext_vector_type(8))) short short8;
typedef __attribute__((ext_vector_type(4))) float f32x4;
typedef unsigned short u16;
typedef unsigned int u32;

__device__ __forceinline__ u16 f2bf(float x) {
    u32 u = __float_as_uint(x);
    return (u16)((u + 0x7FFFu + ((u >> 16) & 1u)) >> 16);
}

// ---------------- all 3 gates: out = pe * sigmoid(pe @ W + b)
__global__ void gates3_kernel(const float* __restrict__ poi,
                              const float* __restrict__ w0, const float* __restrict__ b0,
                              const float* __restrict__ w1, const float* __restrict__ b1,
                              const float* __restrict__ w2, const float* __restrict__ b2,
                              float* __restrict__ o0, float* __restrict__ o1, float* __restrict__ o2) {
    __shared__ float W[3][64][64];
    __shared__ float Bv[3][64];
    __shared__ float pe[4][64];
    int tid = threadIdx.x;
    for (int t = tid; t < 4096; t += 256) {
        int k = t >> 6, j = t & 63;
        W[0][k][j] = w0[t]; W[1][k][j] = w1[t]; W[2][k][j] = w2[t];
    }
    if (tid < 64) { Bv[0][tid] = b0[tid]; Bv[1][tid] = b1[tid]; Bv[2][tid] = b2[tid]; }
    int r0 = blockIdx.x * 4;
    {
        int r = tid >> 6, k = tid & 63;
        pe[r][k] = poi[(r0 + r) * 64 + k];
    }
    __syncthreads();
    int r = tid >> 6, j = tid & 63;
    float pj = pe[r][j];
    int o = (r0 + r) * 64 + j;
    float out[3];
#pragma unroll
    for (int g = 0; g < 3; g++) {
        float acc = Bv[g][j];
#pragma unroll
        for (int k = 0; k < 64; k++) acc += pe[r][k] * W[g][k][j];
        out[g] = pj * (1.0f / (1.0f + __expf(-acc)));
    }
    o0[o] = out[0]; o1[o] = out[1]; o2[o] = out[2];
}

// ================= CSR build =================
// LDS-partial histogram: NO global atomics. 176 blocks.
__global__ __launch_bounds__(256) void hist_lds_kernel(
        const int* __restrict__ r0, const int* __restrict__ r1,
        const int* __restrict__ r2, const int* __restrict__ r3,
        const int* __restrict__ r4, int* __restrict__ part) {
    __shared__ int h[PN];   // 40 KiB
    int b = blockIdx.x, tid = threadIdx.x;
    const int* rows; int n; int l; int* pp;
    if (b < 32)       { rows = r0; n = PN; l = b;       pp = part + PT_GEO + l * PN; }
    else if (b < 64)  { rows = r1; n = PN; l = b - 32;  pp = part + PT_TAR + l * PN; }
    else if (b < 96)  { rows = r2; n = PN; l = b - 64;  pp = part + PT_SRC + l * PN; }
    else if (b < 136) { rows = r3; n = UN; l = b - 96;  pp = part + PT_UP  + l * UN; }
    else              { rows = r4; n = PN; l = b - 136; pp = part + PT_PU  + l * PN; }
    for (int i = tid; i < n; i += 256) h[i] = 0;
    __syncthreads();
    int base4 = l * 2500;   // 10000 edges per block
    for (int j = tid; j < 2500; j += 256) {
        int4 rv = ((const int4*)rows)[base4 + j];
        atomicAdd(&h[rv.x], 1);
        atomicAdd(&h[rv.y], 1);
        atomicAdd(&h[rv.z], 1);
        atomicAdd(&h[rv.w], 1);
    }
    __syncthreads();
    for (int i = tid; i < n; i += 256) pp[i] = h[i];
}

// sum partials per row -> row totals (coalesced, massively parallel).
__global__ __launch_bounds__(256) void sum_partials_kernel(const int* __restrict__ part,
                                                           int* __restrict__ t0, int* __restrict__ t1,
                                                           int* __restrict__ t2, int* __restrict__ t3,
                                                           int* __restrict__ t4) {
    int t = blockIdx.x * 256 + threadIdx.x;
    const int* pp; int* tot; int n; int W; int i;
    if (t < 10000)      { pp = part + PT_GEO; tot = t0; n = PN; W = HW_P; i = t; }
    else if (t < 20000) { pp = part + PT_TAR; tot = t1; n = PN; W = HW_P; i = t - 10000; }
    else if (t < 30000) { pp = part + PT_SRC; tot = t2; n = PN; W = HW_P; i = t - 20000; }
    else if (t < 38000) { pp = part + PT_UP;  tot = t3; n = UN; W = HW_U; i = t - 30000; }
    else if (t < 48000) { pp = part + PT_PU;  tot = t4; n = PN; W = HW_U; i = t - 38000; }
    else return;
    int s = 0;
    for (int w = 0; w < W; w++) s += pp[w * n + i];
    tot[i] = s;
}

// scan: LDS-staged exclusive scan of row totals -> rp, + bucket cursor init
__global__ __launch_bounds__(1024) void scan_lds_kernel(
        const int* __restrict__ t0, const int* __restrict__ t1,
        const int* __restrict__ t2, const int* __restrict__ t3,
        const int* __restrict__ t4,
        int* p0, int* p1, int* p2, int* p3, int* p4, int* __restrict__ bcur) {
    __shared__ int h[PN];      // 40 KiB (counts, then exclusive prefix)
    __shared__ int ps[1024];
    const int* tot; int* rp; int n; int nnz; int rpb;
    switch (blockIdx.x) {
        case 0: tot = t0; rp = p0; n = PN; nnz = NGE;  rpb = RPB_P; break;
        case 1: tot = t1; rp = p1; n = PN; nnz = NDE;  rpb = RPB_P; break;
        case 2: tot = t2; rp = p2; n = PN; nnz = NDE;  rpb = RPB_P; break;
        case 3: tot = t3; rp = p3; n = UN; nnz = NUE;  rpb = RPB_U; break;
        default: tot = t4; rp = p4; n = PN; nnz = NPUE; rpb = RPB_P; break;
    }
    int tid = threadIdx.x;
    for (int i = tid; i < n; i += 1024) h[i] = tot[i];   // coalesced
    __syncthreads();
    int chunk = (n + 1023) >> 10;   // 10 (P) or 8 (U)
    int base = tid * chunk;
    int s = 0;
#pragma unroll
    for (int k = 0; k < 10; k++) {
        int i = base + k;
        if (k < chunk && i < n) s += h[i];
    }
    ps[tid] = s;
    __syncthreads();
    for (int off = 1; off < 1024; off <<= 1) {
        int v = (tid >= off) ? ps[tid - off] : 0;
        __syncthreads();
        ps[tid] += v;
        __syncthreads();
    }
    int pre = (tid > 0) ? ps[tid - 1] : 0;
#pragma unroll
    for (int k = 0; k < 10; k++) {
        int i = base + k;
        if (k < chunk && i < n) {
            int c = h[i];
            rp[i] = pre;
            h[i] = pre;     // keep exclusive prefix in LDS for bcur
            pre += c;
        }
    }
    if (tid == 0) rp[n] = nnz;
    __syncthreads();
    if (tid < 128) {
        int r = tid * rpb; if (r > n) r = n;
        bcur[blockIdx.x * 128 + tid] = (r == n) ? nnz : h[r];
    }
}

// ======== scatter pass 1: bin edges into temp bucket regions ========
// temp entry: .x = (row<<16)|col, .y = val bits
__global__ __launch_bounds__(256) void scatter_p1_kernel(
        const int* __restrict__ r0, const int* __restrict__ k0, const float* __restrict__ v0, int2* __restrict__ t0,
        const int* __restrict__ r1, const int* __restrict__ k1, const float* __restrict__ v1, int2* __restrict__ t1,
        const int* __restrict__ r2, const int* __restrict__ k2, const float* __restrict__ v2, int2* __restrict__ t2,
        const int* __restrict__ r3, const int* __restrict__ k3, const float* __restrict__ v3, int2* __restrict__ t3,
        const int* __restrict__ r4, const int* __restrict__ k4, const float* __restrict__ v4, int2* __restrict__ t4,
        int* __restrict__ bcur) {
    __shared__ int cnt[128];
    __shared__ int2 stage[128 * 64];   // 64 KiB
    int tid = threadIdx.x;
    int c = blockIdx.x;
    const int* rr; const int* cc; const float* vv; int2* tt; int n; int lc; int m; u32 magic;
    if (c < NC_A)      { rr = r0; cc = k0; vv = v0; tt = t0; n = NGE;  lc = c;        m = 0; magic = MAGIC_P; }
    else if (c < NC_B) { rr = r1; cc = k1; vv = v1; tt = t1; n = NDE;  lc = c - NC_A; m = 1; magic = MAGIC_P; }
    else if (c < NC_C) { rr = r2; cc = k2; vv = v2; tt = t2; n = NDE;  lc = c - NC_B; m = 2; magic = MAGIC_P; }
    else if (c < NC_D) { rr = r3; cc = k3; vv = v3; tt = t3; n = NUE;  lc = c - NC_C; m = 3; magic = MAGIC_U; }
    else               { rr = r4; cc = k4; vv = v4; tt = t4; n = NPUE; lc = c - NC_D; m = 4; magic = MAGIC_P; }
    if (tid < 128) cnt[tid] = 0;
    __syncthreads();
    int* gc = bcur + (m << 7);
    int base4 = lc * (SCHUNK / 4);
#pragma unroll
    for (int s = 0; s < 4; s++) {
        int e4i = base4 + s * 256 + tid;
        if (e4i * 4 < n) {    // n % 4 == 0 for all matrices
            int4   rv = ((const int4*)rr)[e4i];
            int4   cv = ((const int4*)cc)[e4i];
            float4 wv = ((const float4*)vv)[e4i];
            int rws[4] = {rv.x, rv.y, rv.z, rv.w};
            int cls[4] = {cv.x, cv.y, cv.z, cv.w};
            float vls[4] = {wv.x, wv.y, wv.z, wv.w};
#pragma unroll
            for (int q = 0; q < 4; q++) {
                int row = rws[q];
                int b = (int)(((u32)row * magic) >> 22);
                int2 ent = make_int2((row << 16) | cls[q], __float_as_int(vls[q]));
                int sl = atomicAdd(&cnt[b], 1);
                if (sl < 64) stage[(b << 6) + sl] = ent;
                else { int p = atomicAdd(&gc[b], 1); tt[p] = ent; }  // rare spill
            }
        }
    }
    __syncthreads();
    if (tid < 128) {
        int cc2 = cnt[tid]; if (cc2 > 64) cc2 = 64;
        if (cc2 > 0) {
            int p = atomicAdd(&gc[tid], cc2);
            for (int k = 0; k < cc2; k++) tt[p + k] = stage[(tid << 6) + k];
        }
    }
}

// ======== scatter pass 2: per-bucket local scatter to final CSR ========
__global__ __launch_bounds__(256) void scatter_p2_kernel(
        const int* __restrict__ rp0, const int2* __restrict__ t0, int2* __restrict__ e0,
        const int* __restrict__ rp1, const int2* __restrict__ t1, int2* __restrict__ e1,
        const int* __restrict__ rp2, const int2* __restrict__ t2, int2* __restrict__ e2,
        const int* __restrict__ rp3, const int2* __restrict__ t3, int2* __restrict__ e3,
        const int* __restrict__ rp4, const int2* __restrict__ t4, int2* __restrict__ e4) {
    __shared__ int lcur[RPB_P];
    int blk = blockIdx.x;
    int m = blk >> 7, b = blk & 127;
    const int* rp; const int2* tp; int2* en; int nrows; int rpb;
    switch (m) {
        case 0: rp = rp0; tp = t0; en = e0; nrows = PN; rpb = RPB_P; break;
        case 1: rp = rp1; tp = t1; en = e1; nrows = PN; rpb = RPB_P; break;
        case 2: rp = rp2; tp = t2; en = e2; nrows = PN; rpb = RPB_P; break;
        case 3: rp = rp3; tp = t3; en = e3; nrows = UN; rpb = RPB_U; break;
        default: rp = rp4; tp = t4; en = e4; nrows = PN; rpb = RPB_P; break;
    }
    int r0 = b * rpb;
    if (r0 >= nrows) return;
    int r1 = r0 + rpb; if (r1 > nrows) r1 = nrows;
    int nr = r1 - r0;
    int tid = threadIdx.x;
    if (tid < nr) lcur[tid] = rp[r0 + tid];
    __syncthreads();
    int s = rp[r0], e = rp[r1];
    for (int k = s + tid; k < e; k += 256) {
        int2 t = tp[k];
        int row = (int)(((u32)t.x) >> 16);
        int col = t.x & 0xFFFF;
        int p = atomicAdd(&lcur[row - r0], 1);
        en[p] = make_int2(col, t.y);
    }
}

// ================= multi-job CSR SpMM (wave per row) =================
struct SpmmJob {
    const int* rp; const int2* ent; const float* x; const float* add;
    const float* avg_a; const float* avg_b; float* y; u16* yb;
    int nrows; int mode;
};

__device__ __forceinline__ float spmm_row_acc(const int2* __restrict__ ent,
                                              const float* __restrict__ x,
                                              int s, int e, int lane, float acc) {
    int p = s;
    for (; p + 8 <= e; p += 8) {
        int2 c0 = ent[p], c1 = ent[p + 1], c2 = ent[p + 2], c3 = ent[p + 3];
        int2 c4 = ent[p + 4], c5 = ent[p + 5], c6 = ent[p + 6], c7 = ent[p + 7];
        float w0 = x[(size_t)c0.x * 64 + lane];
        float w1 = x[(size_t)c1.x * 64 + lane];
        float w2 = x[(size_t)c2.x * 64 + lane];
        float w3 = x[(size_t)c3.x * 64 + lane];
        float w4 = x[(size_t)c4.x * 64 + lane];
        float w5 = x[(size_t)c5.x * 64 + lane];
        float w6 = x[(size_t)c6.x * 64 + lane];
        float w7 = x[(size_t)c7.x * 64 + lane];
        acc = fmaf(__int_as_float(c0.y), w0, acc);
        acc = fmaf(__int_as_float(c1.y), w1, acc);
        acc = fmaf(__int_as_float(c2.y), w2, acc);
        acc = fmaf(__int_as_float(c3.y), w3, acc);
        acc = fmaf(__int_as_float(c4.y), w4, acc);
        acc = fmaf(__int_as_float(c5.y), w5, acc);
        acc = fmaf(__int_as_float(c6.y), w6, acc);
        acc = fmaf(__int_as_float(c7.y), w7, acc);
    }
    for (; p + 4 <= e; p += 4) {
        int2 c0 = ent[p], c1 = ent[p + 1], c2 = ent[p + 2], c3 = ent[p + 3];
        float w0 = x[(size_t)c0.x * 64 + lane];
        float w1 = x[(size_t)c1.x * 64 + lane];
        float w2 = x[(size_t)c2.x * 64 + lane];
        float w3 = x[(size_t)c3.x * 64 + lane];
        acc = fmaf(__int_as_float(c0.y), w0, acc);
        acc = fmaf(__int_as_float(c1.y), w1, acc);
        acc = fmaf(__int_as_float(c2.y), w2, acc);
        acc = fmaf(__int_as_float(c3.y), w3, acc);
    }
    for (; p < e; ++p) {
        int2 c = ent[p];
        acc = fmaf(__int_as_float(c.y), x[(size_t)c.x * 64 + lane], acc);
    }
    return acc;
}

__global__ void spmm_jobs_kernel(SpmmJob ja, SpmmJob jb, int nb0) {
    bool first = ((int)blockIdx.x < nb0);
    SpmmJob J; int blk;
    if (first) { J = ja; blk = blockIdx.x; }
    else       { J = jb; blk = blockIdx.x - nb0; }
    int lane = threadIdx.x & 63;
    int row = blk * 4 + (threadIdx.x >> 6);
    if (row >= J.nrows) return;
    size_t o = (size_t)row * 64 + lane;
    float acc = J.add ? J.add[o] : 0.0f;
    acc = spmm_row_acc(J.ent, J.x, J.rp[row], J.rp[row + 1], lane, acc);
    if (J.mode == 0) { J.y[o] = acc; return; }
    float v = (J.avg_a[o] + J.avg_b[o] + acc) * (1.0f / 3.0f);
    float ss = v * v;
#pragma unroll
    for (int off = 32; off > 0; off >>= 1) ss += __shfl_xor(ss, off, 64);
    float d = fmaxf(sqrtf(ss), 1e-12f);
    float r = v / d;
    J.y[o] = r;
    J.yb[o] = f2bf(r * SCALE_BF);   // pre-scale: infonce epilogue is bare exp2
}

// ===== fuse_users_spmm: 16 rows/block; m_poi spmm + transposed-msg matmul =====
// Old form issued (1 fw load + 1 FMA) per k PER ROW (8000 waves x 448 x 2 instr
// = 47us issue-bound). Now each wave produces 4 rows per fw load:
// per k: 1 fw load + 1 b128 LDS broadcast + 4 FMA. msgt stride 20 floats keeps
// [k][4w] 16B-aligned (80k+16w) and spreads write banks 8-way.
__global__ __launch_bounds__(256) void fuse_users_spmm_kernel(
        const int* __restrict__ rp, const int2* __restrict__ ent,
        const float* __restrict__ xc,
        const float* __restrict__ mg, const float* __restrict__ ms,
        const float* __restrict__ fw, const float* __restrict__ fb,
        const float* __restrict__ ue, float* __restrict__ hg) {
    __shared__ __align__(16) float msgt[448][20];   // 35840 B, [k][row_local]
    int tid = threadIdx.x, lane = tid & 63, w = tid >> 6;
    int base = blockIdx.x * 16;
#pragma unroll
    for (int i = 0; i < 4; i++) {
        int rl = w * 4 + i;
        int row = base + rl;
        size_t o = (size_t)row * 64 + lane;
        float a2 = spmm_row_acc(ent, xc, rp[row], rp[row + 1], lane, 0.0f);  // m_poi
        float a0 = mg[o], a1 = ms[o];
        msgt[0 * 64 + lane][rl] = a0;
        msgt[1 * 64 + lane][rl] = a1;
        msgt[2 * 64 + lane][rl] = a2;
        msgt[3 * 64 + lane][rl] = a0 * a1;
        msgt[4 * 64 + lane][rl] = a0 * a2;
        msgt[5 * 64 + lane][rl] = a1 * a2;
        msgt[6 * 64 + lane][rl] = a0 * a1 * a2;
    }
    __syncthreads();
    float fbv = fb[lane];
    float acc0 = fbv, acc1 = fbv, acc2 = fbv, acc3 = fbv;
#pragma unroll 4
    for (int k = 0; k < 448; k++) {
        float wv = fw[k * 64 + lane];
        float4 m = *(const float4*)&msgt[k][w * 4];   // broadcast read
        acc0 = fmaf(m.x, wv, acc0);
        acc1 = fmaf(m.y, wv, acc1);
        acc2 = fmaf(m.z, wv, acc2);
        acc3 = fmaf(m.w, wv, acc3);
    }
    float accs[4] = {acc0, acc1, acc2, acc3};
#pragma unroll
    for (int i = 0; i < 4; i++) {
        int row = base + w * 4 + i;
        size_t o = (size_t)row * 64 + lane;
        float u = ue[o];
        hg[o] = accs[i] + u + accs[i] * u;
    }
}

// ================= pu spmm + col_g add + fusion_out epilogue =================
__global__ void pu_out_kernel(const int* __restrict__ rp, const int2* __restrict__ ent,
                              const float* __restrict__ hg, const float* __restrict__ colg,
                              const float* __restrict__ ng, const float* __restrict__ ns,
                              float* __restrict__ fuse, float* __restrict__ outp) {
    int lane = threadIdx.x & 63;
    int row = blockIdx.x * 4 + (threadIdx.x >> 6);
    size_t o = (size_t)row * 64 + lane;
    float acc = spmm_row_acc(ent, hg, rp[row], rp[row + 1], lane, colg[o]);
    float ss = acc * acc;
#pragma unroll
    for (int off = 32; off > 0; off >>= 1) ss += __shfl_xor(ss, off, 64);
    float d = fmaxf(sqrtf(ss), 1e-12f);
    float f = acc / d + ng[o] + ns[o];
    fuse[o] = f;
    outp[o] = f;
}

// ================= MFMA InfoNCE, striped non-atomic partials =================
// Inputs pre-scaled by SCALE_BF so acc already includes 5*log2(e):
// e = exp2(acc) = exp(dot*5). __builtin_amdgcn_exp2f -> v_exp_f32 (D=2^S0).
__global__ __launch_bounds__(256) void infonce_mfma_kernel(
        const u16* __restrict__ Ab, const u16* __restrict__ Bb,
        float* __restrict__ rowpart, float* __restrict__ colpart, float* __restrict__ pos) {
    __shared__ __align__(16) char smraw[36864];
    __shared__ float colred[4][64];
    u16* Al = (u16*)smraw;
    u16* Bl = (u16*)(smraw + 18432);
    float* red = (float*)smraw;
    int tid = threadIdx.x;
    int i0 = blockIdx.x * 128, j0 = blockIdx.y * 128;
    const uint4 zero4 = make_uint4(0, 0, 0, 0);
    for (int u = tid; u < 1024; u += 256) {
        int row = u >> 3, ch = u & 7;
        int ga = i0 + row, gb = j0 + row;
        uint4 va = (ga < PN) ? ((const uint4*)Ab)[(size_t)ga * 8 + ch] : zero4;
        uint4 vb = (gb < PN) ? ((const uint4*)Bb)[(size_t)gb * 8 + ch] : zero4;
        ((uint4*)Al)[row * 9 + ch] = va;
        ((uint4*)Bl)[row * 9 + ch] = vb;
    }
    __syncthreads();
    int wv = tid >> 6, lane = tid & 63;
    int wr = (wv & 1) * 64;
    int wc = (wv >> 1) * 64;
    int quad = lane >> 4, l15 = lane & 15;

    short8 af[4][2], bf[4][2];
#pragma unroll
    for (int t = 0; t < 4; t++)
#pragma unroll
        for (int ks = 0; ks < 2; ks++) {
            af[t][ks] = *(const short8*)&Al[(wr + t * 16 + l15) * 72 + ks * 32 + quad * 8];
            bf[t][ks] = *(const short8*)&Bl[(wc + t * 16 + l15) * 72 + ks * 32 + quad * 8];
        }
    __syncthreads();   // frags in regs; LDS (red) reusable after this

    f32x4 acc[4][4];
#pragma unroll
    for (int rt = 0; rt < 4; rt++)
#pragma unroll
        for (int ct = 0; ct < 4; ct++) {
            f32x4 c = {0.f, 0.f, 0.f, 0.f};
            c = __builtin_amdgcn_mfma_f32_16x16x32_bf16(af[rt][0], bf[ct][0], c, 0, 0, 0);
            c = __builtin_amdgcn_mfma_f32_16x16x32_bf16(af[rt][1], bf[ct][1], c, 0, 0, 0);
            acc[rt][ct] = c;
        }

    float rs[4][4];
#pragma unroll
    for (int rt = 0; rt < 4; rt++)
#pragma unroll
        for (int g = 0; g < 4; g++) rs[rt][g] = 0.f;
    float cs[4] = {0.f, 0.f, 0.f, 0.f};

    bool interior = (i0 + 128 <= PN) && (j0 + 128 <= PN) && (i0 != j0);
    if (interior) {
#pragma unroll
        for (int rt = 0; rt < 4; rt++)
#pragma unroll
            for (int ct = 0; ct < 4; ct++) {
                float csum = 0.f;
#pragma unroll
                for (int g = 0; g < 4; g++) {
                    float e = __builtin_amdgcn_exp2f(acc[rt][ct][g]);
                    rs[rt][g] += e;
                    csum += e;
                }
                cs[ct] += csum;
            }
    } else {
#pragma unroll
        for (int rt = 0; rt < 4; rt++) {
            int ibase = i0 + wr + rt * 16 + quad * 4;
#pragma unroll
            for (int ct = 0; ct < 4; ct++) {
                int j = j0 + wc + ct * 16 + l15;
                bool jv = (j < PN);
                float csum = 0.f;
#pragma unroll
                for (int g = 0; g < 4; g++) {
                    int i = ibase + g;
                    float e = 0.f;
                    if (jv && i < PN) {
                        e = __builtin_amdgcn_exp2f(acc[rt][ct][g]);
                        if (i == j) pos[i] = e;
                    }
                    rs[rt][g] += e;
                    csum += e;
                }
                cs[ct] += csum;
            }
        }
    }
    // col partial: reduce across quads (xor 16,32), stage per-wave (no race)
#pragma unroll
    for (int off = 16; off <= 32; off <<= 1)
#pragma unroll
        for (int ct = 0; ct < 4; ct++) cs[ct] += __shfl_xor(cs[ct], off, 64);
    if (quad == 0) {
#pragma unroll
        for (int ct = 0; ct < 4; ct++) colred[wv][ct * 16 + l15] = cs[ct];
    }
    // row partial: LDS transpose stage (unique (slot,rl) owner per thread)
    int slot = (wv >> 1) * 16 + l15;
#pragma unroll
    for (int rt = 0; rt < 4; rt++)
#pragma unroll
        for (int g = 0; g < 4; g++) {
            int rl = wr + rt * 16 + quad * 4 + g;
            red[slot * 131 + rl] = rs[rt][g];
        }
    __syncthreads();
    if (tid < 128) {
        // rowpart
        float sum = 0.f;
#pragma unroll
        for (int s2 = 0; s2 < 32; s2++) sum += red[s2 * 131 + tid];
        int i = i0 + tid;
        if (i < PN) rowpart[(size_t)blockIdx.y * PN + i] = sum;
        // colpart: combine wave pair (0+1 -> cols 0..63, 2+3 -> cols 64..127)
        int half = tid >> 6, jl = tid & 63;
        float cv = colred[half * 2 + 0][jl] + colred[half * 2 + 1][jl];
        int j = j0 + half * 64 + jl;
        if (j < PN) colpart[(size_t)blockIdx.x * PN + j] = cv;
    }
}

// reduce striped partials -> rowsum/colsum (coalesced column sums)
__global__ __launch_bounds__(256) void reduce_sums_kernel(
        const float* __restrict__ rowpart, const float* __restrict__ colpart,
        float* __restrict__ rowsum, float* __restrict__ colsum) {
    int t = blockIdx.x * 256 + threadIdx.x;
    if (t >= 2 * PN) return;
    const float* src; float* dst; int i;
    if (t < PN) { src = rowpart; dst = rowsum; i = t; }
    else        { src = colpart; dst = colsum; i = t - PN; }
    float s = 0.f;
    for (int w = 0; w < NSTR; w++) s += src[(size_t)w * PN + i];
    dst[i] = s;
}

// ====== batch: per-batch-row up-spmm (users_struct[idx[b]]) + norm + loss ======
__global__ void batch_spmm_loss_kernel(const int* __restrict__ rp, const int2* __restrict__ ent,
                                       const float* __restrict__ x, const int* __restrict__ idx,
                                       float* __restrict__ outb, const float* __restrict__ pos,
                                       const float* __restrict__ n1, const float* __restrict__ n2,
                                       float* __restrict__ outl) {
    __shared__ float red[256];
    int tid = threadIdx.x;
    if ((int)blockIdx.x < 1024) {
        int lane = tid & 63;
        int b = blockIdx.x * 4 + (tid >> 6);
        int r = idx[b];
        float v = spmm_row_acc(ent, x, rp[r], rp[r + 1], lane, 0.0f);
        float s = v * v;
#pragma unroll
        for (int off = 32; off > 0; off >>= 1) s += __shfl_xor(s, off, 64);
        float d = fmaxf(sqrtf(s), 1e-12f);
        outb[(size_t)b * 64 + lane] = v / d;
        return;
    }
    float acc = 0.0f;
    for (int i = tid; i < PN; i += 256) {
        float p = pos[i];
        acc += -logf(p / (n1[i] + 1e-8f) + 1e-8f);
        acc += -logf(p / (n2[i] + 1e-8f) + 1e-8f);
    }
    red[tid] = acc;
    __syncthreads();
    for (int s = 128; s > 0; s >>= 1) {
        if (tid < s) red[tid] += red[tid + s];
        __syncthreads();
    }
    if (tid == 0) outl[0] = 0.5f * red[0] / (float)PN;
}

extern "C" void kernel_launch(void* const* d_in, const int* in_sizes, int n_in,
                              void* d_out, int out_size, void* d_ws, size_t ws_size,
                              hipStream_t stream) {
    (void)in_sizes; (void)n_in; (void)out_size; (void)ws_size;
    const float* poi  = (const float*)d_in[0];
    const float* uemb = (const float*)d_in[1];
    const float* wgg  = (const float*)d_in[2];
    const float* bgg  = (const float*)d_in[3];
    const float* wgs  = (const float*)d_in[4];
    const float* bgs  = (const float*)d_in[5];
    const float* wgc  = (const float*)d_in[6];
    const float* bgc  = (const float*)d_in[7];
    const float* fw   = (const float*)d_in[8];
    const float* fb   = (const float*)d_in[9];
    const float* geo_vals = (const float*)d_in[10];
    const float* src_vals = (const float*)d_in[11];
    const float* tar_vals = (const float*)d_in[12];
    const float* up_vals  = (const float*)d_in[13];
    const float* pu_vals  = (const float*)d_in[14];
    const int* geo_rows = (const int*)d_in[15];
    const int* geo_cols = (const int*)d_in[16];
    const int* src_rows = (const int*)d_in[17];
    const int* src_cols = (const int*)d_in[18];
    const int* tar_rows = (const int*)d_in[19];
    const int* tar_cols = (const int*)d_in[20];
    const int* up_rows  = (const int*)d_in[21];
    const int* up_cols  = (const int*)d_in[22];
    const int* pu_rows  = (const int*)d_in[23];
    const int* pu_cols  = (const int*)d_in[24];
    const int* user_idx = (const int*)d_in[25];

    const int PD = PN * 64, UD = UN * 64;

    // ---- workspace layout (6 PD pools; ws is 256MiB, we use ~42MB)
    float* F = (float*)d_ws;
    float* rowsum = F;                  // PN
    float* colsum = rowsum + PN;        // PN
    float* pos    = colsum + PN;        // PN
    u16*   ngb    = (u16*)(F + 3 * PN); // PD bf16 (pre-scaled by SCALE_BF)
    u16*   nsb    = ngb + PD;           // PD bf16 (pre-scaled)
    float* U0     = F + 3 * PN + PD;    // UD
    float* P0     = U0 + UD;            // PD pools
    float* P1     = P0 + PD;
    float* P2     = P1 + PD;
    float* P3     = P2 + PD;
    float* P4     = P3 + PD;
    float* P5     = P4 + PD;

    // U0..P5 region time-shared: hist partials (1.68M ints) -> scatter temps
    // (1.76M int2 = 14.1MB <= 17.4MB) -> float pools
    int* part = (int*)U0;
    int2* tmp = (int2*)U0;
    int2* tmp_geo = tmp;
    int2* tmp_tar = tmp_geo + NGE;
    int2* tmp_src = tmp_tar + NDE;
    int2* tmp_up  = tmp_src + NDE;
    int2* tmp_pu  = tmp_up + NUE;

    int* M = (int*)(P5 + PD);           // CSR meta
    int* geo_rp = M;               int* geo_tot = geo_rp + PN + 1;
    int* tar_rp = geo_tot + PN;    int* tar_tot = tar_rp + PN + 1;
    int* src_rp = tar_tot + PN;    int* src_tot = src_rp + PN + 1;
    int* up_rp  = src_tot + PN;    int* up_tot  = up_rp + UN + 1;
    int* pu_rp  = up_tot + UN;     int* pu_tot  = pu_rp + PN + 1;
    int* bcur   = M + 96006;            // 640 bucket cursors
    const int meta_ints = 96646;        // even -> entries stay 8B-aligned
    int2* geo_ent = (int2*)(M + meta_ints);
    int2* tar_ent = geo_ent + NGE;
    int2* src_ent = tar_ent + NDE;
    int2* up_ent  = src_ent + NDE;
    int2* pu_ent  = up_ent + NUE;

    // infonce striped partials overlay the geo/tar/src entry region
    // (dead after step 8): 2 * 79 * PN floats = 6.32MB <= 7.68MB
    float* rowpart = (float*)geo_ent;
    float* colpart = rowpart + (size_t)NSTR * PN;

    float* out_bu = (float*)d_out;
    float* out_fp = out_bu + (size_t)BN * 64;
    float* out_loss = out_fp + (size_t)PN * 64;

    const int RB = PN / 4;     // 2500
    const int UB = UN / 4;     // 2000

    // 1. histogram via LDS partials (176 blocks)
    hist_lds_kernel<<<176, 256, 0, stream>>>(geo_rows, tar_rows, src_rows, up_rows, pu_rows, part);
    // 2a. sum partials per row (coalesced, 188 blocks)
    sum_partials_kernel<<<188, 256, 0, stream>>>(part, geo_tot, tar_tot, src_tot, up_tot, pu_tot);
    // 2b. LDS-staged exclusive scan -> rp + bucket cursors
    scan_lds_kernel<<<5, 1024, 0, stream>>>(geo_tot, tar_tot, src_tot, up_tot, pu_tot,
                                            geo_rp, tar_rp, src_rp, up_rp, pu_rp, bcur);
    // 3a. pass 1: bin into temp bucket regions (sequential-run writes)
    scatter_p1_kernel<<<NCT, 256, 0, stream>>>(
        geo_rows, geo_cols, geo_vals, tmp_geo,
        tar_rows, tar_cols, tar_vals, tmp_tar,
        src_rows, src_cols, src_vals, tmp_src,
        up_rows, up_cols, up_vals, tmp_up,
        pu_rows, pu_cols, pu_vals, tmp_pu,
        bcur);
    // 3b. pass 2: single-writer per-region scatter to final CSR entries
    scatter_p2_kernel<<<640, 256, 0, stream>>>(
        geo_rp, tmp_geo, geo_ent,
        tar_rp, tmp_tar, tar_ent,
        src_rp, tmp_src, src_ent,
        up_rp, tmp_up, up_ent,
        pu_rp, tmp_pu, pu_ent);
    // 4. gates: geo_g->P0, seq_g->P1, col_g->P2 (temp dead from here)
    gates3_kernel<<<RB, 256, 0, stream>>>(poi, wgg, bgg, wgs, bgs, wgc, bgc, P0, P1, P2);

    SpmmJob jz = {};
    // 5. dual: x1_g = A*geo_g + geo_g -> P3   ||   m1 = T*seq_g -> P4
    SpmmJob j_geo1 = {geo_rp, geo_ent, P0, P0, nullptr, nullptr, P3, nullptr, PN, 0};
    SpmmJob j_tar1 = {tar_rp, tar_ent, P1, nullptr, nullptr, nullptr, P4, nullptr, PN, 0};
    spmm_jobs_kernel<<<2 * RB, 256, 0, stream>>>(j_geo1, j_tar1, RB);
    // 6. dual (independent chains): geo-final ng -> P0  ||  x1_s = S*m1 + seq_g -> P5
    SpmmJob j_geo2 = {geo_rp, geo_ent, P3, P3, P0, P3, P0, ngb, PN, 1};
    SpmmJob j_s1   = {src_rp, src_ent, P4, P1, nullptr, nullptr, P5, nullptr, PN, 0};
    spmm_jobs_kernel<<<2 * RB, 256, 0, stream>>>(j_geo2, j_s1, RB);
    // 7. m2 = T*x1_s -> P4 (m1 dead)
    SpmmJob j_tar2 = {tar_rp, tar_ent, P5, nullptr, nullptr, nullptr, P4, nullptr, PN, 0};
    spmm_jobs_kernel<<<RB, 256, 0, stream>>>(j_tar2, jz, RB);
    // 8. ns-final: x2 = S*m2 + x1_s; ns = norm((seq_g+x1_s+x2)/3) -> P1
    SpmmJob j_s2 = {src_rp, src_ent, P4, P5, P1, P5, P1, nsb, PN, 1};
    spmm_jobs_kernel<<<RB, 256, 0, stream>>>(j_s2, jz, RB);
    // 9. InfoNCE (MFMA, striped partials; geo/tar/src entries dead from here)
    dim3 ig(NSTR, NSTR);
    infonce_mfma_kernel<<<ig, 256, 0, stream>>>(ngb, nsb, rowpart, colpart, pos);
    // 9b. reduce partials -> rowsum/colsum
    reduce_sums_kernel<<<(2 * PN + 255) / 256, 256, 0, stream>>>(rowpart, colpart, rowsum, colsum);
    // 10a+b. m_geo = up*ng -> P4 || m_seq = up*ns -> P3 (independent, dual dispatch)
    SpmmJob j_mg = {up_rp, up_ent, P0, nullptr, nullptr, nullptr, P4, nullptr, UN, 0};
    SpmmJob j_ms = {up_rp, up_ent, P1, nullptr, nullptr, nullptr, P3, nullptr, UN, 0};
    spmm_jobs_kernel<<<2 * UB, 256, 0, stream>>>(j_mg, j_ms, UB);
    // 10c. fuse (m_poi spmm inline, 16 rows/block): msg @ fw + user merge -> U0
    fuse_users_spmm_kernel<<<UN / 16, 256, 0, stream>>>(up_rp, up_ent, P2, P4, P3, fw, fb, uemb, U0);
    // 11. hg_pois = col_g + pu*hg; fusion = norm + ng + ns -> P3 + out
    pu_out_kernel<<<RB, 256, 0, stream>>>(pu_rp, pu_ent, U0, P2, P0, P1, P3, out_fp);
    // 12. batch: per-row up-spmm of fusion + norm + loss
    batch_spmm_loss_kernel<<<1025, 256, 0, stream>>>(up_rp, up_ent, P3, user_idx,
                                                     out_bu, pos, rowsum, colsum, out_loss);
}

// Round 15
// 399.985 us; speedup vs baseline: 1.0146x; 1.0146x over previous
//
#include <hip/hip_runtime.h>

#define PN 10000
#define UN 8000
#define BN 4096
#define NGE 320000
#define NDE 320000
#define NUE 400000
#define NPUE 400000
// bf16 inputs pre-scaled by sqrt(5*log2(e)) so infonce epilogue is a bare exp2
#define SCALE_BF 2.6857914f
// cumulative edge offsets: geo, tar, src, up, pu
#define E0 320000
#define E1 640000
#define E2 960000
#define E3 1360000
#define E4 1760000

// bucketed scatter: chunks of 4096 edges, per-matrix chunk counts
#define SCHUNK 4096
#define NC_A 79     // ceil(320000/4096) geo
#define NC_B 158    // + tar
#define NC_C 237    // + src
#define NC_D 335    // + up (98 chunks)
#define NCT 433     // + pu (98 chunks)
// 128 row-buckets per matrix; RPB = rows per bucket
#define RPB_P 79    // 128*79 = 10112 >= 10000
#define RPB_U 63    // 128*63 = 8064  >= 8000
// magic for exact div: b = (row*MAGIC)>>22
#define MAGIC_P 53093u   // ceil(2^22/79)
#define MAGIC_U 66577u   // ceil(2^22/63)

// LDS-partial histogram: 32 blocks per P-matrix, 40 per U-matrix, 10000 edges each
#define HW_P 32
#define HW_U 40
// partial array offsets (ints)
#define PT_GEO 0
#define PT_TAR 320000
#define PT_SRC 640000
#define PT_UP  960000
#define PT_PU  1280000

#define NSTR 79    // infonce stripes per dim

typedef __attribute__((ext_vector_type(8))) short short8;
typedef __attribute__((ext_vector_type(4))) float f32x4;
typedef unsigned short u16;
typedef unsigned int u32;

__device__ __forceinline__ u16 f2bf(float x) {
    u32 u = __float_as_uint(x);
    return (u16)((u + 0x7FFFu + ((u >> 16) & 1u)) >> 16);
}

// ---------------- all 3 gates: out = pe * sigmoid(pe @ W + b)
__global__ void gates3_kernel(const float* __restrict__ poi,
                              const float* __restrict__ w0, const float* __restrict__ b0,
                              const float* __restrict__ w1, const float* __restrict__ b1,
                              const float* __restrict__ w2, const float* __restrict__ b2,
                              float* __restrict__ o0, float* __restrict__ o1, float* __restrict__ o2) {
    __shared__ float W[3][64][64];
    __shared__ float Bv[3][64];
    __shared__ float pe[4][64];
    int tid = threadIdx.x;
    for (int t = tid; t < 4096; t += 256) {
        int k = t >> 6, j = t & 63;
        W[0][k][j] = w0[t]; W[1][k][j] = w1[t]; W[2][k][j] = w2[t];
    }
    if (tid < 64) { Bv[0][tid] = b0[tid]; Bv[1][tid] = b1[tid]; Bv[2][tid] = b2[tid]; }
    int r0 = blockIdx.x * 4;
    {
        int r = tid >> 6, k = tid & 63;
        pe[r][k] = poi[(r0 + r) * 64 + k];
    }
    __syncthreads();
    int r = tid >> 6, j = tid & 63;
    float pj = pe[r][j];
    int o = (r0 + r) * 64 + j;
    float out[3];
#pragma unroll
    for (int g = 0; g < 3; g++) {
        float acc = Bv[g][j];
#pragma unroll
        for (int k = 0; k < 64; k++) acc += pe[r][k] * W[g][k][j];
        out[g] = pj * (1.0f / (1.0f + __expf(-acc)));
    }
    o0[o] = out[0]; o1[o] = out[1]; o2[o] = out[2];
}

// ================= CSR build =================
// LDS-partial histogram: NO global atomics. 176 blocks.
__global__ __launch_bounds__(256) void hist_lds_kernel(
        const int* __restrict__ r0, const int* __restrict__ r1,
        const int* __restrict__ r2, const int* __restrict__ r3,
        const int* __restrict__ r4, int* __restrict__ part) {
    __shared__ int h[PN];   // 40 KiB
    int b = blockIdx.x, tid = threadIdx.x;
    const int* rows; int n; int l; int* pp;
    if (b < 32)       { rows = r0; n = PN; l = b;       pp = part + PT_GEO + l * PN; }
    else if (b < 64)  { rows = r1; n = PN; l = b - 32;  pp = part + PT_TAR + l * PN; }
    else if (b < 96)  { rows = r2; n = PN; l = b - 64;  pp = part + PT_SRC + l * PN; }
    else if (b < 136) { rows = r3; n = UN; l = b - 96;  pp = part + PT_UP  + l * UN; }
    else              { rows = r4; n = PN; l = b - 136; pp = part + PT_PU  + l * PN; }
    for (int i = tid; i < n; i += 256) h[i] = 0;
    __syncthreads();
    int base4 = l * 2500;   // 10000 edges per block
    for (int j = tid; j < 2500; j += 256) {
        int4 rv = ((const int4*)rows)[base4 + j];
        atomicAdd(&h[rv.x], 1);
        atomicAdd(&h[rv.y], 1);
        atomicAdd(&h[rv.z], 1);
        atomicAdd(&h[rv.w], 1);
    }
    __syncthreads();
    for (int i = tid; i < n; i += 256) pp[i] = h[i];
}

// sum partials per row -> row totals (coalesced, massively parallel).
__global__ __launch_bounds__(256) void sum_partials_kernel(const int* __restrict__ part,
                                                           int* __restrict__ t0, int* __restrict__ t1,
                                                           int* __restrict__ t2, int* __restrict__ t3,
                                                           int* __restrict__ t4) {
    int t = blockIdx.x * 256 + threadIdx.x;
    const int* pp; int* tot; int n; int W; int i;
    if (t < 10000)      { pp = part + PT_GEO; tot = t0; n = PN; W = HW_P; i = t; }
    else if (t < 20000) { pp = part + PT_TAR; tot = t1; n = PN; W = HW_P; i = t - 10000; }
    else if (t < 30000) { pp = part + PT_SRC; tot = t2; n = PN; W = HW_P; i = t - 20000; }
    else if (t < 38000) { pp = part + PT_UP;  tot = t3; n = UN; W = HW_U; i = t - 30000; }
    else if (t < 48000) { pp = part + PT_PU;  tot = t4; n = PN; W = HW_U; i = t - 38000; }
    else return;
    int s = 0;
    for (int w = 0; w < W; w++) s += pp[w * n + i];
    tot[i] = s;
}

// scan: LDS-staged exclusive scan of row totals -> rp, + bucket cursor init
__global__ __launch_bounds__(1024) void scan_lds_kernel(
        const int* __restrict__ t0, const int* __restrict__ t1,
        const int* __restrict__ t2, const int* __restrict__ t3,
        const int* __restrict__ t4,
        int* p0, int* p1, int* p2, int* p3, int* p4, int* __restrict__ bcur) {
    __shared__ int h[PN];      // 40 KiB (counts, then exclusive prefix)
    __shared__ int ps[1024];
    const int* tot; int* rp; int n; int nnz; int rpb;
    switch (blockIdx.x) {
        case 0: tot = t0; rp = p0; n = PN; nnz = NGE;  rpb = RPB_P; break;
        case 1: tot = t1; rp = p1; n = PN; nnz = NDE;  rpb = RPB_P; break;
        case 2: tot = t2; rp = p2; n = PN; nnz = NDE;  rpb = RPB_P; break;
        case 3: tot = t3; rp = p3; n = UN; nnz = NUE;  rpb = RPB_U; break;
        default: tot = t4; rp = p4; n = PN; nnz = NPUE; rpb = RPB_P; break;
    }
    int tid = threadIdx.x;
    for (int i = tid; i < n; i += 1024) h[i] = tot[i];   // coalesced
    __syncthreads();
    int chunk = (n + 1023) >> 10;   // 10 (P) or 8 (U)
    int base = tid * chunk;
    int s = 0;
#pragma unroll
    for (int k = 0; k < 10; k++) {
        int i = base + k;
        if (k < chunk && i < n) s += h[i];
    }
    ps[tid] = s;
    __syncthreads();
    for (int off = 1; off < 1024; off <<= 1) {
        int v = (tid >= off) ? ps[tid - off] : 0;
        __syncthreads();
        ps[tid] += v;
        __syncthreads();
    }
    int pre = (tid > 0) ? ps[tid - 1] : 0;
#pragma unroll
    for (int k = 0; k < 10; k++) {
        int i = base + k;
        if (k < chunk && i < n) {
            int c = h[i];
            rp[i] = pre;
            h[i] = pre;     // keep exclusive prefix in LDS for bcur
            pre += c;
        }
    }
    if (tid == 0) rp[n] = nnz;
    __syncthreads();
    if (tid < 128) {
        int r = tid * rpb; if (r > n) r = n;
        bcur[blockIdx.x * 128 + tid] = (r == n) ? nnz : h[r];
    }
}

// ======== scatter pass 1: bin edges into temp bucket regions ========
// temp entry: .x = (row<<16)|col, .y = val bits
__global__ __launch_bounds__(256) void scatter_p1_kernel(
        const int* __restrict__ r0, const int* __restrict__ k0, const float* __restrict__ v0, int2* __restrict__ t0,
        const int* __restrict__ r1, const int* __restrict__ k1, const float* __restrict__ v1, int2* __restrict__ t1,
        const int* __restrict__ r2, const int* __restrict__ k2, const float* __restrict__ v2, int2* __restrict__ t2,
        const int* __restrict__ r3, const int* __restrict__ k3, const float* __restrict__ v3, int2* __restrict__ t3,
        const int* __restrict__ r4, const int* __restrict__ k4, const float* __restrict__ v4, int2* __restrict__ t4,
        int* __restrict__ bcur) {
    __shared__ int cnt[128];
    __shared__ int2 stage[128 * 64];   // 64 KiB
    int tid = threadIdx.x;
    int c = blockIdx.x;
    const int* rr; const int* cc; const float* vv; int2* tt; int n; int lc; int m; u32 magic;
    if (c < NC_A)      { rr = r0; cc = k0; vv = v0; tt = t0; n = NGE;  lc = c;        m = 0; magic = MAGIC_P; }
    else if (c < NC_B) { rr = r1; cc = k1; vv = v1; tt = t1; n = NDE;  lc = c - NC_A; m = 1; magic = MAGIC_P; }
    else if (c < NC_C) { rr = r2; cc = k2; vv = v2; tt = t2; n = NDE;  lc = c - NC_B; m = 2; magic = MAGIC_P; }
    else if (c < NC_D) { rr = r3; cc = k3; vv = v3; tt = t3; n = NUE;  lc = c - NC_C; m = 3; magic = MAGIC_U; }
    else               { rr = r4; cc = k4; vv = v4; tt = t4; n = NPUE; lc = c - NC_D; m = 4; magic = MAGIC_P; }
    if (tid < 128) cnt[tid] = 0;
    __syncthreads();
    int* gc = bcur + (m << 7);
    int base4 = lc * (SCHUNK / 4);
#pragma unroll
    for (int s = 0; s < 4; s++) {
        int e4i = base4 + s * 256 + tid;
        if (e4i * 4 < n) {    // n % 4 == 0 for all matrices
            int4   rv = ((const int4*)rr)[e4i];
            int4   cv = ((const int4*)cc)[e4i];
            float4 wv = ((const float4*)vv)[e4i];
            int rws[4] = {rv.x, rv.y, rv.z, rv.w};
            int cls[4] = {cv.x, cv.y, cv.z, cv.w};
            float vls[4] = {wv.x, wv.y, wv.z, wv.w};
#pragma unroll
            for (int q = 0; q < 4; q++) {
                int row = rws[q];
                int b = (int)(((u32)row * magic) >> 22);
                int2 ent = make_int2((row << 16) | cls[q], __float_as_int(vls[q]));
                int sl = atomicAdd(&cnt[b], 1);
                if (sl < 64) stage[(b << 6) + sl] = ent;
                else { int p = atomicAdd(&gc[b], 1); tt[p] = ent; }  // rare spill
            }
        }
    }
    __syncthreads();
    if (tid < 128) {
        int cc2 = cnt[tid]; if (cc2 > 64) cc2 = 64;
        if (cc2 > 0) {
            int p = atomicAdd(&gc[tid], cc2);
            for (int k = 0; k < cc2; k++) tt[p + k] = stage[(tid << 6) + k];
        }
    }
}

// ======== scatter pass 2: per-bucket local scatter to final CSR ========
__global__ __launch_bounds__(256) void scatter_p2_kernel(
        const int* __restrict__ rp0, const int2* __restrict__ t0, int2* __restrict__ e0,
        const int* __restrict__ rp1, const int2* __restrict__ t1, int2* __restrict__ e1,
        const int* __restrict__ rp2, const int2* __restrict__ t2, int2* __restrict__ e2,
        const int* __restrict__ rp3, const int2* __restrict__ t3, int2* __restrict__ e3,
        const int* __restrict__ rp4, const int2* __restrict__ t4, int2* __restrict__ e4) {
    __shared__ int lcur[RPB_P];
    int blk = blockIdx.x;
    int m = blk >> 7, b = blk & 127;
    const int* rp; const int2* tp; int2* en; int nrows; int rpb;
    switch (m) {
        case 0: rp = rp0; tp = t0; en = e0; nrows = PN; rpb = RPB_P; break;
        case 1: rp = rp1; tp = t1; en = e1; nrows = PN; rpb = RPB_P; break;
        case 2: rp = rp2; tp = t2; en = e2; nrows = PN; rpb = RPB_P; break;
        case 3: rp = rp3; tp = t3; en = e3; nrows = UN; rpb = RPB_U; break;
        default: rp = rp4; tp = t4; en = e4; nrows = PN; rpb = RPB_P; break;
    }
    int r0 = b * rpb;
    if (r0 >= nrows) return;
    int r1 = r0 + rpb; if (r1 > nrows) r1 = nrows;
    int nr = r1 - r0;
    int tid = threadIdx.x;
    if (tid < nr) lcur[tid] = rp[r0 + tid];
    __syncthreads();
    int s = rp[r0], e = rp[r1];
    for (int k = s + tid; k < e; k += 256) {
        int2 t = tp[k];
        int row = (int)(((u32)t.x) >> 16);
        int col = t.x & 0xFFFF;
        int p = atomicAdd(&lcur[row - r0], 1);
        en[p] = make_int2(col, t.y);
    }
}

// ================= multi-job CSR SpMM (wave per row) =================
struct SpmmJob {
    const int* rp; const int2* ent; const float* x; const float* add;
    const float* avg_a; const float* avg_b; float* y; u16* yb;
    int nrows; int mode;
};

__device__ __forceinline__ float spmm_row_acc(const int2* __restrict__ ent,
                                              const float* __restrict__ x,
                                              int s, int e, int lane, float acc) {
    int p = s;
    for (; p + 8 <= e; p += 8) {
        int2 c0 = ent[p], c1 = ent[p + 1], c2 = ent[p + 2], c3 = ent[p + 3];
        int2 c4 = ent[p + 4], c5 = ent[p + 5], c6 = ent[p + 6], c7 = ent[p + 7];
        float w0 = x[(size_t)c0.x * 64 + lane];
        float w1 = x[(size_t)c1.x * 64 + lane];
        float w2 = x[(size_t)c2.x * 64 + lane];
        float w3 = x[(size_t)c3.x * 64 + lane];
        float w4 = x[(size_t)c4.x * 64 + lane];
        float w5 = x[(size_t)c5.x * 64 + lane];
        float w6 = x[(size_t)c6.x * 64 + lane];
        float w7 = x[(size_t)c7.x * 64 + lane];
        acc = fmaf(__int_as_float(c0.y), w0, acc);
        acc = fmaf(__int_as_float(c1.y), w1, acc);
        acc = fmaf(__int_as_float(c2.y), w2, acc);
        acc = fmaf(__int_as_float(c3.y), w3, acc);
        acc = fmaf(__int_as_float(c4.y), w4, acc);
        acc = fmaf(__int_as_float(c5.y), w5, acc);
        acc = fmaf(__int_as_float(c6.y), w6, acc);
        acc = fmaf(__int_as_float(c7.y), w7, acc);
    }
    for (; p + 4 <= e; p += 4) {
        int2 c0 = ent[p], c1 = ent[p + 1], c2 = ent[p + 2], c3 = ent[p + 3];
        float w0 = x[(size_t)c0.x * 64 + lane];
        float w1 = x[(size_t)c1.x * 64 + lane];
        float w2 = x[(size_t)c2.x * 64 + lane];
        float w3 = x[(size_t)c3.x * 64 + lane];
        acc = fmaf(__int_as_float(c0.y), w0, acc);
        acc = fmaf(__int_as_float(c1.y), w1, acc);
        acc = fmaf(__int_as_float(c2.y), w2, acc);
        acc = fmaf(__int_as_float(c3.y), w3, acc);
    }
    for (; p < e; ++p) {
        int2 c = ent[p];
        acc = fmaf(__int_as_float(c.y), x[(size_t)c.x * 64 + lane], acc);
    }
    return acc;
}

__global__ void spmm_jobs_kernel(SpmmJob ja, SpmmJob jb, int nb0) {
    bool first = ((int)blockIdx.x < nb0);
    SpmmJob J; int blk;
    if (first) { J = ja; blk = blockIdx.x; }
    else       { J = jb; blk = blockIdx.x - nb0; }
    int lane = threadIdx.x & 63;
    int row = blk * 4 + (threadIdx.x >> 6);
    if (row >= J.nrows) return;
    size_t o = (size_t)row * 64 + lane;
    float acc = J.add ? J.add[o] : 0.0f;
    acc = spmm_row_acc(J.ent, J.x, J.rp[row], J.rp[row + 1], lane, acc);
    if (J.mode == 0) { J.y[o] = acc; return; }
    float v = (J.avg_a[o] + J.avg_b[o] + acc) * (1.0f / 3.0f);
    float ss = v * v;
#pragma unroll
    for (int off = 32; off > 0; off >>= 1) ss += __shfl_xor(ss, off, 64);
    float d = fmaxf(sqrtf(ss), 1e-12f);
    float r = v / d;
    J.y[o] = r;
    J.yb[o] = f2bf(r * SCALE_BF);   // pre-scale: infonce epilogue is bare exp2
}

// ===== fuse_users_spmm: m_poi spmm + msg @ fw (fw chunked through LDS) =====
// R14 lesson: 4-row-per-wave reuse shrank the grid to 500 blocks (20% occ,
// regression). Keep R13's shape (4 rows/block, 2000 blocks, 60% occ) and get
// the fw reuse by staging fw in 4 LDS chunks of 112x64 shared by the block's
// 4 waves: per-wave global loads in the matmul drop 448 -> 112; inner loop is
// broadcast LDS read + lane-stride-1 LDS read + FMA (conflict-free).
__global__ __launch_bounds__(256) void fuse_users_spmm_kernel(
        const int* __restrict__ rp, const int2* __restrict__ ent,
        const float* __restrict__ xc,
        const float* __restrict__ mg, const float* __restrict__ ms,
        const float* __restrict__ fw, const float* __restrict__ fb,
        const float* __restrict__ ue, float* __restrict__ hg) {
    __shared__ float msg[4][448];        // 7168 B
    __shared__ float fwl[112 * 64];      // 28672 B
    int tid = threadIdx.x, lane = tid & 63, w = tid >> 6;
    int row = blockIdx.x * 4 + w;
    size_t o = (size_t)row * 64 + lane;
    float a2 = spmm_row_acc(ent, xc, rp[row], rp[row + 1], lane, 0.0f);  // m_poi
    float a0 = mg[o], a1 = ms[o];
    msg[w][0 * 64 + lane] = a0;
    msg[w][1 * 64 + lane] = a1;
    msg[w][2 * 64 + lane] = a2;
    msg[w][3 * 64 + lane] = a0 * a1;
    msg[w][4 * 64 + lane] = a0 * a2;
    msg[w][5 * 64 + lane] = a1 * a2;
    msg[w][6 * 64 + lane] = a0 * a1 * a2;
    float acc = fb[lane];
#pragma unroll
    for (int c = 0; c < 4; c++) {
        __syncthreads();   // msg ready (c=0) / previous chunk consumed (c>0)
        for (int t = tid; t < 112 * 64; t += 256) fwl[t] = fw[c * (112 * 64) + t];
        __syncthreads();
        int kb = c * 112;
#pragma unroll 8
        for (int kk = 0; kk < 112; kk++)
            acc = fmaf(msg[w][kb + kk], fwl[kk * 64 + lane], acc);
    }
    float u = ue[o];
    hg[o] = acc + u + acc * u;
}

// ================= pu spmm + col_g add + fusion_out epilogue =================
__global__ void pu_out_kernel(const int* __restrict__ rp, const int2* __restrict__ ent,
                              const float* __restrict__ hg, const float* __restrict__ colg,
                              const float* __restrict__ ng, const float* __restrict__ ns,
                              float* __restrict__ fuse, float* __restrict__ outp) {
    int lane = threadIdx.x & 63;
    int row = blockIdx.x * 4 + (threadIdx.x >> 6);
    size_t o = (size_t)row * 64 + lane;
    float acc = spmm_row_acc(ent, hg, rp[row], rp[row + 1], lane, colg[o]);
    float ss = acc * acc;
#pragma unroll
    for (int off = 32; off > 0; off >>= 1) ss += __shfl_xor(ss, off, 64);
    float d = fmaxf(sqrtf(ss), 1e-12f);
    float f = acc / d + ng[o] + ns[o];
    fuse[o] = f;
    outp[o] = f;
}

// ================= MFMA InfoNCE, striped non-atomic partials =================
__global__ __launch_bounds__(256) void infonce_mfma_kernel(
        const u16* __restrict__ Ab, const u16* __restrict__ Bb,
        float* __restrict__ rowpart, float* __restrict__ colpart, float* __restrict__ pos) {
    __shared__ __align__(16) char smraw[36864];
    __shared__ float colred[4][64];
    u16* Al = (u16*)smraw;
    u16* Bl = (u16*)(smraw + 18432);
    float* red = (float*)smraw;
    int tid = threadIdx.x;
    int i0 = blockIdx.x * 128, j0 = blockIdx.y * 128;
    const uint4 zero4 = make_uint4(0, 0, 0, 0);
    for (int u = tid; u < 1024; u += 256) {
        int row = u >> 3, ch = u & 7;
        int ga = i0 + row, gb = j0 + row;
        uint4 va = (ga < PN) ? ((const uint4*)Ab)[(size_t)ga * 8 + ch] : zero4;
        uint4 vb = (gb < PN) ? ((const uint4*)Bb)[(size_t)gb * 8 + ch] : zero4;
        ((uint4*)Al)[row * 9 + ch] = va;
        ((uint4*)Bl)[row * 9 + ch] = vb;
    }
    __syncthreads();
    int wv = tid >> 6, lane = tid & 63;
    int wr = (wv & 1) * 64;
    int wc = (wv >> 1) * 64;
    int quad = lane >> 4, l15 = lane & 15;

    short8 af[4][2], bf[4][2];
#pragma unroll
    for (int t = 0; t < 4; t++)
#pragma unroll
        for (int ks = 0; ks < 2; ks++) {
            af[t][ks] = *(const short8*)&Al[(wr + t * 16 + l15) * 72 + ks * 32 + quad * 8];
            bf[t][ks] = *(const short8*)&Bl[(wc + t * 16 + l15) * 72 + ks * 32 + quad * 8];
        }
    __syncthreads();   // frags in regs; LDS (red) reusable after this

    f32x4 acc[4][4];
#pragma unroll
    for (int rt = 0; rt < 4; rt++)
#pragma unroll
        for (int ct = 0; ct < 4; ct++) {
            f32x4 c = {0.f, 0.f, 0.f, 0.f};
            c = __builtin_amdgcn_mfma_f32_16x16x32_bf16(af[rt][0], bf[ct][0], c, 0, 0, 0);
            c = __builtin_amdgcn_mfma_f32_16x16x32_bf16(af[rt][1], bf[ct][1], c, 0, 0, 0);
            acc[rt][ct] = c;
        }

    float rs[4][4];
#pragma unroll
    for (int rt = 0; rt < 4; rt++)
#pragma unroll
        for (int g = 0; g < 4; g++) rs[rt][g] = 0.f;
    float cs[4] = {0.f, 0.f, 0.f, 0.f};

    bool interior = (i0 + 128 <= PN) && (j0 + 128 <= PN) && (i0 != j0);
    if (interior) {
#pragma unroll
        for (int rt = 0; rt < 4; rt++)
#pragma unroll
            for (int ct = 0; ct < 4; ct++) {
                float csum = 0.f;
#pragma unroll
                for (int g = 0; g < 4; g++) {
                    float e = __builtin_amdgcn_exp2f(acc[rt][ct][g]);
                    rs[rt][g] += e;
                    csum += e;
                }
                cs[ct] += csum;
            }
    } else {
#pragma unroll
        for (int rt = 0; rt < 4; rt++) {
            int ibase = i0 + wr + rt * 16 + quad * 4;
#pragma unroll
            for (int ct = 0; ct < 4; ct++) {
                int j = j0 + wc + ct * 16 + l15;
                bool jv = (j < PN);
                float csum = 0.f;
#pragma unroll
                for (int g = 0; g < 4; g++) {
                    int i = ibase + g;
                    float e = 0.f;
                    if (jv && i < PN) {
                        e = __builtin_amdgcn_exp2f(acc[rt][ct][g]);
                        if (i == j) pos[i] = e;
                    }
                    rs[rt][g] += e;
                    csum += e;
                }
                cs[ct] += csum;
            }
        }
    }
    // col partial: reduce across quads (xor 16,32), stage per-wave (no race)
#pragma unroll
    for (int off = 16; off <= 32; off <<= 1)
#pragma unroll
        for (int ct = 0; ct < 4; ct++) cs[ct] += __shfl_xor(cs[ct], off, 64);
    if (quad == 0) {
#pragma unroll
        for (int ct = 0; ct < 4; ct++) colred[wv][ct * 16 + l15] = cs[ct];
    }
    // row partial: LDS transpose stage (unique (slot,rl) owner per thread)
    int slot = (wv >> 1) * 16 + l15;
#pragma unroll
    for (int rt = 0; rt < 4; rt++)
#pragma unroll
        for (int g = 0; g < 4; g++) {
            int rl = wr + rt * 16 + quad * 4 + g;
            red[slot * 131 + rl] = rs[rt][g];
        }
    __syncthreads();
    if (tid < 128) {
        // rowpart
        float sum = 0.f;
#pragma unroll
        for (int s2 = 0; s2 < 32; s2++) sum += red[s2 * 131 + tid];
        int i = i0 + tid;
        if (i < PN) rowpart[(size_t)blockIdx.y * PN + i] = sum;
        // colpart: combine wave pair (0+1 -> cols 0..63, 2+3 -> cols 64..127)
        int half = tid >> 6, jl = tid & 63;
        float cv = colred[half * 2 + 0][jl] + colred[half * 2 + 1][jl];
        int j = j0 + half * 64 + jl;
        if (j < PN) colpart[(size_t)blockIdx.x * PN + j] = cv;
    }
}

// reduce striped partials -> rowsum/colsum (coalesced column sums)
__global__ __launch_bounds__(256) void reduce_sums_kernel(
        const float* __restrict__ rowpart, const float* __restrict__ colpart,
        float* __restrict__ rowsum, float* __restrict__ colsum) {
    int t = blockIdx.x * 256 + threadIdx.x;
    if (t >= 2 * PN) return;
    const float* src; float* dst; int i;
    if (t < PN) { src = rowpart; dst = rowsum; i = t; }
    else        { src = colpart; dst = colsum; i = t - PN; }
    float s = 0.f;
    for (int w = 0; w < NSTR; w++) s += src[(size_t)w * PN + i];
    dst[i] = s;
}

// ====== batch: per-batch-row up-spmm (users_struct[idx[b]]) + norm + loss ======
__global__ void batch_spmm_loss_kernel(const int* __restrict__ rp, const int2* __restrict__ ent,
                                       const float* __restrict__ x, const int* __restrict__ idx,
                                       float* __restrict__ outb, const float* __restrict__ pos,
                                       const float* __restrict__ n1, const float* __restrict__ n2,
                                       float* __restrict__ outl) {
    __shared__ float red[256];
    int tid = threadIdx.x;
    if ((int)blockIdx.x < 1024) {
        int lane = tid & 63;
        int b = blockIdx.x * 4 + (tid >> 6);
        int r = idx[b];
        float v = spmm_row_acc(ent, x, rp[r], rp[r + 1], lane, 0.0f);
        float s = v * v;
#pragma unroll
        for (int off = 32; off > 0; off >>= 1) s += __shfl_xor(s, off, 64);
        float d = fmaxf(sqrtf(s), 1e-12f);
        outb[(size_t)b * 64 + lane] = v / d;
        return;
    }
    float acc = 0.0f;
    for (int i = tid; i < PN; i += 256) {
        float p = pos[i];
        acc += -logf(p / (n1[i] + 1e-8f) + 1e-8f);
        acc += -logf(p / (n2[i] + 1e-8f) + 1e-8f);
    }
    red[tid] = acc;
    __syncthreads();
    for (int s = 128; s > 0; s >>= 1) {
        if (tid < s) red[tid] += red[tid + s];
        __syncthreads();
    }
    if (tid == 0) outl[0] = 0.5f * red[0] / (float)PN;
}

extern "C" void kernel_launch(void* const* d_in, const int* in_sizes, int n_in,
                              void* d_out, int out_size, void* d_ws, size_t ws_size,
                              hipStream_t stream) {
    (void)in_sizes; (void)n_in; (void)out_size; (void)ws_size;
    const float* poi  = (const float*)d_in[0];
    const float* uemb = (const float*)d_in[1];
    const float* wgg  = (const float*)d_in[2];
    const float* bgg  = (const float*)d_in[3];
    const float* wgs  = (const float*)d_in[4];
    const float* bgs  = (const float*)d_in[5];
    const float* wgc  = (const float*)d_in[6];
    const float* bgc  = (const float*)d_in[7];
    const float* fw   = (const float*)d_in[8];
    const float* fb   = (const float*)d_in[9];
    const float* geo_vals = (const float*)d_in[10];
    const float* src_vals = (const float*)d_in[11];
    const float* tar_vals = (const float*)d_in[12];
    const float* up_vals  = (const float*)d_in[13];
    const float* pu_vals  = (const float*)d_in[14];
    const int* geo_rows = (const int*)d_in[15];
    const int* geo_cols = (const int*)d_in[16];
    const int* src_rows = (const int*)d_in[17];
    const int* src_cols = (const int*)d_in[18];
    const int* tar_rows = (const int*)d_in[19];
    const int* tar_cols = (const int*)d_in[20];
    const int* up_rows  = (const int*)d_in[21];
    const int* up_cols  = (const int*)d_in[22];
    const int* pu_rows  = (const int*)d_in[23];
    const int* pu_cols  = (const int*)d_in[24];
    const int* user_idx = (const int*)d_in[25];

    const int PD = PN * 64, UD = UN * 64;

    // ---- workspace layout (6 PD pools; ws is 256MiB, we use ~42MB)
    float* F = (float*)d_ws;
    float* rowsum = F;                  // PN
    float* colsum = rowsum + PN;        // PN
    float* pos    = colsum + PN;        // PN
    u16*   ngb    = (u16*)(F + 3 * PN); // PD bf16 (pre-scaled by SCALE_BF)
    u16*   nsb    = ngb + PD;           // PD bf16 (pre-scaled)
    float* U0     = F + 3 * PN + PD;    // UD
    float* P0     = U0 + UD;            // PD pools
    float* P1     = P0 + PD;
    float* P2     = P1 + PD;
    float* P3     = P2 + PD;
    float* P4     = P3 + PD;
    float* P5     = P4 + PD;

    // U0..P5 region time-shared: hist partials (1.68M ints) -> scatter temps
    // (1.76M int2 = 14.1MB <= 17.4MB) -> float pools
    int* part = (int*)U0;
    int2* tmp = (int2*)U0;
    int2* tmp_geo = tmp;
    int2* tmp_tar = tmp_geo + NGE;
    int2* tmp_src = tmp_tar + NDE;
    int2* tmp_up  = tmp_src + NDE;
    int2* tmp_pu  = tmp_up + NUE;

    int* M = (int*)(P5 + PD);           // CSR meta
    int* geo_rp = M;               int* geo_tot = geo_rp + PN + 1;
    int* tar_rp = geo_tot + PN;    int* tar_tot = tar_rp + PN + 1;
    int* src_rp = tar_tot + PN;    int* src_tot = src_rp + PN + 1;
    int* up_rp  = src_tot + PN;    int* up_tot  = up_rp + UN + 1;
    int* pu_rp  = up_tot + UN;     int* pu_tot  = pu_rp + PN + 1;
    int* bcur   = M + 96006;            // 640 bucket cursors
    const int meta_ints = 96646;        // even -> entries stay 8B-aligned
    int2* geo_ent = (int2*)(M + meta_ints);
    int2* tar_ent = geo_ent + NGE;
    int2* src_ent = tar_ent + NDE;
    int2* up_ent  = src_ent + NDE;
    int2* pu_ent  = up_ent + NUE;

    // infonce striped partials overlay the geo/tar/src entry region
    // (dead after step 8): 2 * 79 * PN floats = 6.32MB <= 7.68MB
    float* rowpart = (float*)geo_ent;
    float* colpart = rowpart + (size_t)NSTR * PN;

    float* out_bu = (float*)d_out;
    float* out_fp = out_bu + (size_t)BN * 64;
    float* out_loss = out_fp + (size_t)PN * 64;

    const int RB = PN / 4;     // 2500
    const int UB = UN / 4;     // 2000

    // 1. histogram via LDS partials (176 blocks)
    hist_lds_kernel<<<176, 256, 0, stream>>>(geo_rows, tar_rows, src_rows, up_rows, pu_rows, part);
    // 2a. sum partials per row (coalesced, 188 blocks)
    sum_partials_kernel<<<188, 256, 0, stream>>>(part, geo_tot, tar_tot, src_tot, up_tot, pu_tot);
    // 2b. LDS-staged exclusive scan -> rp + bucket cursors
    scan_lds_kernel<<<5, 1024, 0, stream>>>(geo_tot, tar_tot, src_tot, up_tot, pu_tot,
                                            geo_rp, tar_rp, src_rp, up_rp, pu_rp, bcur);
    // 3a. pass 1: bin into temp bucket regions (sequential-run writes)
    scatter_p1_kernel<<<NCT, 256, 0, stream>>>(
        geo_rows, geo_cols, geo_vals, tmp_geo,
        tar_rows, tar_cols, tar_vals, tmp_tar,
        src_rows, src_cols, src_vals, tmp_src,
        up_rows, up_cols, up_vals, tmp_up,
        pu_rows, pu_cols, pu_vals, tmp_pu,
        bcur);
    // 3b. pass 2: single-writer per-region scatter to final CSR entries
    scatter_p2_kernel<<<640, 256, 0, stream>>>(
        geo_rp, tmp_geo, geo_ent,
        tar_rp, tmp_tar, tar_ent,
        src_rp, tmp_src, src_ent,
        up_rp, tmp_up, up_ent,
        pu_rp, tmp_pu, pu_ent);
    // 4. gates: geo_g->P0, seq_g->P1, col_g->P2 (temp dead from here)
    gates3_kernel<<<RB, 256, 0, stream>>>(poi, wgg, bgg, wgs, bgs, wgc, bgc, P0, P1, P2);

    SpmmJob jz = {};
    // 5. dual: x1_g = A*geo_g + geo_g -> P3   ||   m1 = T*seq_g -> P4
    SpmmJob j_geo1 = {geo_rp, geo_ent, P0, P0, nullptr, nullptr, P3, nullptr, PN, 0};
    SpmmJob j_tar1 = {tar_rp, tar_ent, P1, nullptr, nullptr, nullptr, P4, nullptr, PN, 0};
    spmm_jobs_kernel<<<2 * RB, 256, 0, stream>>>(j_geo1, j_tar1, RB);
    // 6. dual (independent chains): geo-final ng -> P0  ||  x1_s = S*m1 + seq_g -> P5
    SpmmJob j_geo2 = {geo_rp, geo_ent, P3, P3, P0, P3, P0, ngb, PN, 1};
    SpmmJob j_s1   = {src_rp, src_ent, P4, P1, nullptr, nullptr, P5, nullptr, PN, 0};
    spmm_jobs_kernel<<<2 * RB, 256, 0, stream>>>(j_geo2, j_s1, RB);
    // 7. m2 = T*x1_s -> P4 (m1 dead)
    SpmmJob j_tar2 = {tar_rp, tar_ent, P5, nullptr, nullptr, nullptr, P4, nullptr, PN, 0};
    spmm_jobs_kernel<<<RB, 256, 0, stream>>>(j_tar2, jz, RB);
    // 8. ns-final: x2 = S*m2 + x1_s; ns = norm((seq_g+x1_s+x2)/3) -> P1
    SpmmJob j_s2 = {src_rp, src_ent, P4, P5, P1, P5, P1, nsb, PN, 1};
    spmm_jobs_kernel<<<RB, 256, 0, stream>>>(j_s2, jz, RB);
    // 9. InfoNCE (MFMA, striped partials; geo/tar/src entries dead from here)
    dim3 ig(NSTR, NSTR);
    infonce_mfma_kernel<<<ig, 256, 0, stream>>>(ngb, nsb, rowpart, colpart, pos);
    // 9b. reduce partials -> rowsum/colsum
    reduce_sums_kernel<<<(2 * PN + 255) / 256, 256, 0, stream>>>(rowpart, colpart, rowsum, colsum);
    // 10a+b. m_geo = up*ng -> P4 || m_seq = up*ns -> P3 (independent, dual dispatch)
    SpmmJob j_mg = {up_rp, up_ent, P0, nullptr, nullptr, nullptr, P4, nullptr, UN, 0};
    SpmmJob j_ms = {up_rp, up_ent, P1, nullptr, nullptr, nullptr, P3, nullptr, UN, 0};
    spmm_jobs_kernel<<<2 * UB, 256, 0, stream>>>(j_mg, j_ms, UB);
    // 10c. fuse (m_poi spmm inline, 4 rows/block, fw chunked via LDS) -> U0
    fuse_users_spmm_kernel<<<UB, 256, 0, stream>>>(up_rp, up_ent, P2, P4, P3, fw, fb, uemb, U0);
    // 11. hg_pois = col_g + pu*hg; fusion = norm + ng + ns -> P3 + out
    pu_out_kernel<<<RB, 256, 0, stream>>>(pu_rp, pu_ent, U0, P2, P0, P1, P3, out_fp);
    // 12. batch: per-row up-spmm of fusion + norm + loss
    batch_spmm_loss_kernel<<<1025, 256, 0, stream>>>(up_rp, up_ent, P3, user_idx,
                                                     out_bu, pos, rowsum, colsum, out_loss);
}

// Round 16
// 386.554 us; speedup vs baseline: 1.0498x; 1.0347x over previous
//
#include <hip/hip_runtime.h>

#define PN 10000
#define UN 8000
#define BN 4096
#define NGE 320000
#define NDE 320000
#define NUE 400000
#define NPUE 400000
// bf16 inputs pre-scaled by sqrt(5*log2(e)) so infonce epilogue is a bare exp2
#define SCALE_BF 2.6857914f
// cumulative edge offsets: geo, tar, src, up, pu
#define E0 320000
#define E1 640000
#define E2 960000
#define E3 1360000
#define E4 1760000

// bucketed scatter: chunks of 4096 edges, per-matrix chunk counts
#define SCHUNK 4096
#define NC_A 79     // ceil(320000/4096) geo
#define NC_B 158    // + tar
#define NC_C 237    // + src
#define NC_D 335    // + up (98 chunks)
#define NCT 433     // + pu (98 chunks)
// 128 row-buckets per matrix; RPB = rows per bucket
#define RPB_P 79    // 128*79 = 10112 >= 10000
#define RPB_U 63    // 128*63 = 8064  >= 8000
// magic for exact div: b = (row*MAGIC)>>22
#define MAGIC_P 53093u   // ceil(2^22/79)
#define MAGIC_U 66577u   // ceil(2^22/63)

// LDS-partial histogram: 32 blocks per P-matrix, 40 per U-matrix, 10000 edges each
#define HW_P 32
#define HW_U 40
// partial array offsets (ints)
#define PT_GEO 0
#define PT_TAR 320000
#define PT_SRC 640000
#define PT_UP  960000
#define PT_PU  1280000

#define NSTR 79    // infonce stripes per dim

typedef __attribute__((ext_vector_type(8))) short short8;
typedef __attribute__((ext_vector_type(4))) float f32x4;
typedef unsigned short u16;
typedef unsigned int u32;

__device__ __forceinline__ u16 f2bf(float x) {
    u32 u = __float_as_uint(x);
    return (u16)((u + 0x7FFFu + ((u >> 16) & 1u)) >> 16);
}

// ---------------- all 3 gates: out = pe * sigmoid(pe @ W + b)
__global__ void gates3_kernel(const float* __restrict__ poi,
                              const float* __restrict__ w0, const float* __restrict__ b0,
                              const float* __restrict__ w1, const float* __restrict__ b1,
                              const float* __restrict__ w2, const float* __restrict__ b2,
                              float* __restrict__ o0, float* __restrict__ o1, float* __restrict__ o2) {
    __shared__ float W[3][64][64];
    __shared__ float Bv[3][64];
    __shared__ float pe[4][64];
    int tid = threadIdx.x;
    for (int t = tid; t < 4096; t += 256) {
        int k = t >> 6, j = t & 63;
        W[0][k][j] = w0[t]; W[1][k][j] = w1[t]; W[2][k][j] = w2[t];
    }
    if (tid < 64) { Bv[0][tid] = b0[tid]; Bv[1][tid] = b1[tid]; Bv[2][tid] = b2[tid]; }
    int r0 = blockIdx.x * 4;
    {
        int r = tid >> 6, k = tid & 63;
        pe[r][k] = poi[(r0 + r) * 64 + k];
    }
    __syncthreads();
    int r = tid >> 6, j = tid & 63;
    float pj = pe[r][j];
    int o = (r0 + r) * 64 + j;
    float out[3];
#pragma unroll
    for (int g = 0; g < 3; g++) {
        float acc = Bv[g][j];
#pragma unroll
        for (int k = 0; k < 64; k++) acc += pe[r][k] * W[g][k][j];
        out[g] = pj * (1.0f / (1.0f + __expf(-acc)));
    }
    o0[o] = out[0]; o1[o] = out[1]; o2[o] = out[2];
}

// ================= CSR build =================
// LDS-partial histogram: NO global atomics. 176 blocks.
__global__ __launch_bounds__(256) void hist_lds_kernel(
        const int* __restrict__ r0, const int* __restrict__ r1,
        const int* __restrict__ r2, const int* __restrict__ r3,
        const int* __restrict__ r4, int* __restrict__ part) {
    __shared__ int h[PN];   // 40 KiB
    int b = blockIdx.x, tid = threadIdx.x;
    const int* rows; int n; int l; int* pp;
    if (b < 32)       { rows = r0; n = PN; l = b;       pp = part + PT_GEO + l * PN; }
    else if (b < 64)  { rows = r1; n = PN; l = b - 32;  pp = part + PT_TAR + l * PN; }
    else if (b < 96)  { rows = r2; n = PN; l = b - 64;  pp = part + PT_SRC + l * PN; }
    else if (b < 136) { rows = r3; n = UN; l = b - 96;  pp = part + PT_UP  + l * UN; }
    else              { rows = r4; n = PN; l = b - 136; pp = part + PT_PU  + l * PN; }
    for (int i = tid; i < n; i += 256) h[i] = 0;
    __syncthreads();
    int base4 = l * 2500;   // 10000 edges per block
    for (int j = tid; j < 2500; j += 256) {
        int4 rv = ((const int4*)rows)[base4 + j];
        atomicAdd(&h[rv.x], 1);
        atomicAdd(&h[rv.y], 1);
        atomicAdd(&h[rv.z], 1);
        atomicAdd(&h[rv.w], 1);
    }
    __syncthreads();
    for (int i = tid; i < n; i += 256) pp[i] = h[i];
}

// sum partials per row -> row totals (coalesced, massively parallel).
__global__ __launch_bounds__(256) void sum_partials_kernel(const int* __restrict__ part,
                                                           int* __restrict__ t0, int* __restrict__ t1,
                                                           int* __restrict__ t2, int* __restrict__ t3,
                                                           int* __restrict__ t4) {
    int t = blockIdx.x * 256 + threadIdx.x;
    const int* pp; int* tot; int n; int W; int i;
    if (t < 10000)      { pp = part + PT_GEO; tot = t0; n = PN; W = HW_P; i = t; }
    else if (t < 20000) { pp = part + PT_TAR; tot = t1; n = PN; W = HW_P; i = t - 10000; }
    else if (t < 30000) { pp = part + PT_SRC; tot = t2; n = PN; W = HW_P; i = t - 20000; }
    else if (t < 38000) { pp = part + PT_UP;  tot = t3; n = UN; W = HW_U; i = t - 30000; }
    else if (t < 48000) { pp = part + PT_PU;  tot = t4; n = PN; W = HW_U; i = t - 38000; }
    else return;
    int s = 0;
    for (int w = 0; w < W; w++) s += pp[w * n + i];
    tot[i] = s;
}

// scan: LDS-staged exclusive scan of row totals -> rp, + bucket cursor init
__global__ __launch_bounds__(1024) void scan_lds_kernel(
        const int* __restrict__ t0, const int* __restrict__ t1,
        const int* __restrict__ t2, const int* __restrict__ t3,
        const int* __restrict__ t4,
        int* p0, int* p1, int* p2, int* p3, int* p4, int* __restrict__ bcur) {
    __shared__ int h[PN];      // 40 KiB (counts, then exclusive prefix)
    __shared__ int ps[1024];
    const int* tot; int* rp; int n; int nnz; int rpb;
    switch (blockIdx.x) {
        case 0: tot = t0; rp = p0; n = PN; nnz = NGE;  rpb = RPB_P; break;
        case 1: tot = t1; rp = p1; n = PN; nnz = NDE;  rpb = RPB_P; break;
        case 2: tot = t2; rp = p2; n = PN; nnz = NDE;  rpb = RPB_P; break;
        case 3: tot = t3; rp = p3; n = UN; nnz = NUE;  rpb = RPB_U; break;
        default: tot = t4; rp = p4; n = PN; nnz = NPUE; rpb = RPB_P; break;
    }
    int tid = threadIdx.x;
    for (int i = tid; i < n; i += 1024) h[i] = tot[i];   // coalesced
    __syncthreads();
    int chunk = (n + 1023) >> 10;   // 10 (P) or 8 (U)
    int base = tid * chunk;
    int s = 0;
#pragma unroll
    for (int k = 0; k < 10; k++) {
        int i = base + k;
        if (k < chunk && i < n) s += h[i];
    }
    ps[tid] = s;
    __syncthreads();
    for (int off = 1; off < 1024; off <<= 1) {
        int v = (tid >= off) ? ps[tid - off] : 0;
        __syncthreads();
        ps[tid] += v;
        __syncthreads();
    }
    int pre = (tid > 0) ? ps[tid - 1] : 0;
#pragma unroll
    for (int k = 0; k < 10; k++) {
        int i = base + k;
        if (k < chunk && i < n) {
            int c = h[i];
            rp[i] = pre;
            h[i] = pre;     // keep exclusive prefix in LDS for bcur
            pre += c;
        }
    }
    if (tid == 0) rp[n] = nnz;
    __syncthreads();
    if (tid < 128) {
        int r = tid * rpb; if (r > n) r = n;
        bcur[blockIdx.x * 128 + tid] = (r == n) ? nnz : h[r];
    }
}

// ======== scatter pass 1: bin edges into temp bucket regions ========
// temp entry: .x = (row<<16)|col, .y = val bits
__global__ __launch_bounds__(256) void scatter_p1_kernel(
        const int* __restrict__ r0, const int* __restrict__ k0, const float* __restrict__ v0, int2* __restrict__ t0,
        const int* __restrict__ r1, const int* __restrict__ k1, const float* __restrict__ v1, int2* __restrict__ t1,
        const int* __restrict__ r2, const int* __restrict__ k2, const float* __restrict__ v2, int2* __restrict__ t2,
        const int* __restrict__ r3, const int* __restrict__ k3, const float* __restrict__ v3, int2* __restrict__ t3,
        const int* __restrict__ r4, const int* __restrict__ k4, const float* __restrict__ v4, int2* __restrict__ t4,
        int* __restrict__ bcur) {
    __shared__ int cnt[128];
    __shared__ int2 stage[128 * 64];   // 64 KiB
    int tid = threadIdx.x;
    int c = blockIdx.x;
    const int* rr; const int* cc; const float* vv; int2* tt; int n; int lc; int m; u32 magic;
    if (c < NC_A)      { rr = r0; cc = k0; vv = v0; tt = t0; n = NGE;  lc = c;        m = 0; magic = MAGIC_P; }
    else if (c < NC_B) { rr = r1; cc = k1; vv = v1; tt = t1; n = NDE;  lc = c - NC_A; m = 1; magic = MAGIC_P; }
    else if (c < NC_C) { rr = r2; cc = k2; vv = v2; tt = t2; n = NDE;  lc = c - NC_B; m = 2; magic = MAGIC_P; }
    else if (c < NC_D) { rr = r3; cc = k3; vv = v3; tt = t3; n = NUE;  lc = c - NC_C; m = 3; magic = MAGIC_U; }
    else               { rr = r4; cc = k4; vv = v4; tt = t4; n = NPUE; lc = c - NC_D; m = 4; magic = MAGIC_P; }
    if (tid < 128) cnt[tid] = 0;
    __syncthreads();
    int* gc = bcur + (m << 7);
    int base4 = lc * (SCHUNK / 4);
#pragma unroll
    for (int s = 0; s < 4; s++) {
        int e4i = base4 + s * 256 + tid;
        if (e4i * 4 < n) {    // n % 4 == 0 for all matrices
            int4   rv = ((const int4*)rr)[e4i];
            int4   cv = ((const int4*)cc)[e4i];
            float4 wv = ((const float4*)vv)[e4i];
            int rws[4] = {rv.x, rv.y, rv.z, rv.w};
            int cls[4] = {cv.x, cv.y, cv.z, cv.w};
            float vls[4] = {wv.x, wv.y, wv.z, wv.w};
#pragma unroll
            for (int q = 0; q < 4; q++) {
                int row = rws[q];
                int b = (int)(((u32)row * magic) >> 22);
                int2 ent = make_int2((row << 16) | cls[q], __float_as_int(vls[q]));
                int sl = atomicAdd(&cnt[b], 1);
                if (sl < 64) stage[(b << 6) + sl] = ent;
                else { int p = atomicAdd(&gc[b], 1); tt[p] = ent; }  // rare spill
            }
        }
    }
    __syncthreads();
    if (tid < 128) {
        int cc2 = cnt[tid]; if (cc2 > 64) cc2 = 64;
        if (cc2 > 0) {
            int p = atomicAdd(&gc[tid], cc2);
            for (int k = 0; k < cc2; k++) tt[p + k] = stage[(tid << 6) + k];
        }
    }
}

// ======== scatter pass 2: per-bucket local scatter to final CSR ========
__global__ __launch_bounds__(256) void scatter_p2_kernel(
        const int* __restrict__ rp0, const int2* __restrict__ t0, int2* __restrict__ e0,
        const int* __restrict__ rp1, const int2* __restrict__ t1, int2* __restrict__ e1,
        const int* __restrict__ rp2, const int2* __restrict__ t2, int2* __restrict__ e2,
        const int* __restrict__ rp3, const int2* __restrict__ t3, int2* __restrict__ e3,
        const int* __restrict__ rp4, const int2* __restrict__ t4, int2* __restrict__ e4) {
    __shared__ int lcur[RPB_P];
    int blk = blockIdx.x;
    int m = blk >> 7, b = blk & 127;
    const int* rp; const int2* tp; int2* en; int nrows; int rpb;
    switch (m) {
        case 0: rp = rp0; tp = t0; en = e0; nrows = PN; rpb = RPB_P; break;
        case 1: rp = rp1; tp = t1; en = e1; nrows = PN; rpb = RPB_P; break;
        case 2: rp = rp2; tp = t2; en = e2; nrows = PN; rpb = RPB_P; break;
        case 3: rp = rp3; tp = t3; en = e3; nrows = UN; rpb = RPB_U; break;
        default: rp = rp4; tp = t4; en = e4; nrows = PN; rpb = RPB_P; break;
    }
    int r0 = b * rpb;
    if (r0 >= nrows) return;
    int r1 = r0 + rpb; if (r1 > nrows) r1 = nrows;
    int nr = r1 - r0;
    int tid = threadIdx.x;
    if (tid < nr) lcur[tid] = rp[r0 + tid];
    __syncthreads();
    int s = rp[r0], e = rp[r1];
    for (int k = s + tid; k < e; k += 256) {
        int2 t = tp[k];
        int row = (int)(((u32)t.x) >> 16);
        int col = t.x & 0xFFFF;
        int p = atomicAdd(&lcur[row - r0], 1);
        en[p] = make_int2(col, t.y);
    }
}

// ================= multi-job CSR SpMM (wave per row) =================
struct SpmmJob {
    const int* rp; const int2* ent; const float* x; const float* add;
    const float* avg_a; const float* avg_b; float* y; u16* yb;
    int nrows; int mode;
};

__device__ __forceinline__ float spmm_row_acc(const int2* __restrict__ ent,
                                              const float* __restrict__ x,
                                              int s, int e, int lane, float acc) {
    int p = s;
    for (; p + 8 <= e; p += 8) {
        int2 c0 = ent[p], c1 = ent[p + 1], c2 = ent[p + 2], c3 = ent[p + 3];
        int2 c4 = ent[p + 4], c5 = ent[p + 5], c6 = ent[p + 6], c7 = ent[p + 7];
        float w0 = x[(size_t)c0.x * 64 + lane];
        float w1 = x[(size_t)c1.x * 64 + lane];
        float w2 = x[(size_t)c2.x * 64 + lane];
        float w3 = x[(size_t)c3.x * 64 + lane];
        float w4 = x[(size_t)c4.x * 64 + lane];
        float w5 = x[(size_t)c5.x * 64 + lane];
        float w6 = x[(size_t)c6.x * 64 + lane];
        float w7 = x[(size_t)c7.x * 64 + lane];
        acc = fmaf(__int_as_float(c0.y), w0, acc);
        acc = fmaf(__int_as_float(c1.y), w1, acc);
        acc = fmaf(__int_as_float(c2.y), w2, acc);
        acc = fmaf(__int_as_float(c3.y), w3, acc);
        acc = fmaf(__int_as_float(c4.y), w4, acc);
        acc = fmaf(__int_as_float(c5.y), w5, acc);
        acc = fmaf(__int_as_float(c6.y), w6, acc);
        acc = fmaf(__int_as_float(c7.y), w7, acc);
    }
    for (; p + 4 <= e; p += 4) {
        int2 c0 = ent[p], c1 = ent[p + 1], c2 = ent[p + 2], c3 = ent[p + 3];
        float w0 = x[(size_t)c0.x * 64 + lane];
        float w1 = x[(size_t)c1.x * 64 + lane];
        float w2 = x[(size_t)c2.x * 64 + lane];
        float w3 = x[(size_t)c3.x * 64 + lane];
        acc = fmaf(__int_as_float(c0.y), w0, acc);
        acc = fmaf(__int_as_float(c1.y), w1, acc);
        acc = fmaf(__int_as_float(c2.y), w2, acc);
        acc = fmaf(__int_as_float(c3.y), w3, acc);
    }
    for (; p < e; ++p) {
        int2 c = ent[p];
        acc = fmaf(__int_as_float(c.y), x[(size_t)c.x * 64 + lane], acc);
    }
    return acc;
}

__global__ void spmm_jobs_kernel(SpmmJob ja, SpmmJob jb, int nb0) {
    bool first = ((int)blockIdx.x < nb0);
    SpmmJob J; int blk;
    if (first) { J = ja; blk = blockIdx.x; }
    else       { J = jb; blk = blockIdx.x - nb0; }
    int lane = threadIdx.x & 63;
    int row = blk * 4 + (threadIdx.x >> 6);
    if (row >= J.nrows) return;
    size_t o = (size_t)row * 64 + lane;
    float acc = J.add ? J.add[o] : 0.0f;
    acc = spmm_row_acc(J.ent, J.x, J.rp[row], J.rp[row + 1], lane, acc);
    if (J.mode == 0) { J.y[o] = acc; return; }
    float v = (J.avg_a[o] + J.avg_b[o] + acc) * (1.0f / 3.0f);
    float ss = v * v;
#pragma unroll
    for (int off = 32; off > 0; off >>= 1) ss += __shfl_xor(ss, off, 64);
    float d = fmaxf(sqrtf(ss), 1e-12f);
    float r = v / d;
    J.y[o] = r;
    J.yb[o] = f2bf(r * SCALE_BF);   // pre-scale: infonce epilogue is bare exp2
}

// ===== fuse_users_spmm: 2 rows/wave, 8 rows/block; m_poi spmm + msg @ fw =====
// R13 (1 row/wave, plain fw loads): 47us, issue+L2-bound (916MB fw L2 reads).
// R14 (4 rows/wave): occupancy collapse. R15 (fw via LDS chunks): 35% occ, 52us.
// This: grid 1000, 4000 waves (slot-limited occupancy preserved, LDS only
// 14.3KB), per k = 1 fw load + 2 LDS broadcasts + 2 FMA -> fw L2 traffic
// halves, issue volume -17%. Per-row k-order unchanged (bit-identical).
__global__ __launch_bounds__(256) void fuse_users_spmm_kernel(
        const int* __restrict__ rp, const int2* __restrict__ ent,
        const float* __restrict__ xc,
        const float* __restrict__ mg, const float* __restrict__ ms,
        const float* __restrict__ fw, const float* __restrict__ fb,
        const float* __restrict__ ue, float* __restrict__ hg) {
    __shared__ float msg[8][448];   // 14336 B
    int tid = threadIdx.x, lane = tid & 63, w = tid >> 6;
    int base = blockIdx.x * 8;
#pragma unroll
    for (int i = 0; i < 2; i++) {
        int rl = w * 2 + i;
        int row = base + rl;
        size_t o = (size_t)row * 64 + lane;
        float a2 = spmm_row_acc(ent, xc, rp[row], rp[row + 1], lane, 0.0f);  // m_poi
        float a0 = mg[o], a1 = ms[o];
        msg[rl][0 * 64 + lane] = a0;
        msg[rl][1 * 64 + lane] = a1;
        msg[rl][2 * 64 + lane] = a2;
        msg[rl][3 * 64 + lane] = a0 * a1;
        msg[rl][4 * 64 + lane] = a0 * a2;
        msg[rl][5 * 64 + lane] = a1 * a2;
        msg[rl][6 * 64 + lane] = a0 * a1 * a2;
    }
    __syncthreads();
    float fbv = fb[lane];
    float acc0 = fbv, acc1 = fbv;
    int r0 = w * 2, r1 = w * 2 + 1;
#pragma unroll 8
    for (int k = 0; k < 448; k++) {
        float wv = fw[k * 64 + lane];
        acc0 = fmaf(msg[r0][k], wv, acc0);
        acc1 = fmaf(msg[r1][k], wv, acc1);
    }
    {
        size_t o = (size_t)(base + r0) * 64 + lane;
        float u = ue[o];
        hg[o] = acc0 + u + acc0 * u;
    }
    {
        size_t o = (size_t)(base + r1) * 64 + lane;
        float u = ue[o];
        hg[o] = acc1 + u + acc1 * u;
    }
}

// ================= pu spmm + col_g add + fusion_out epilogue =================
__global__ void pu_out_kernel(const int* __restrict__ rp, const int2* __restrict__ ent,
                              const float* __restrict__ hg, const float* __restrict__ colg,
                              const float* __restrict__ ng, const float* __restrict__ ns,
                              float* __restrict__ fuse, float* __restrict__ outp) {
    int lane = threadIdx.x & 63;
    int row = blockIdx.x * 4 + (threadIdx.x >> 6);
    size_t o = (size_t)row * 64 + lane;
    float acc = spmm_row_acc(ent, hg, rp[row], rp[row + 1], lane, colg[o]);
    float ss = acc * acc;
#pragma unroll
    for (int off = 32; off > 0; off >>= 1) ss += __shfl_xor(ss, off, 64);
    float d = fmaxf(sqrtf(ss), 1e-12f);
    float f = acc / d + ng[o] + ns[o];
    fuse[o] = f;
    outp[o] = f;
}

// ================= MFMA InfoNCE, striped non-atomic partials =================
__global__ __launch_bounds__(256) void infonce_mfma_kernel(
        const u16* __restrict__ Ab, const u16* __restrict__ Bb,
        float* __restrict__ rowpart, float* __restrict__ colpart, float* __restrict__ pos) {
    __shared__ __align__(16) char smraw[36864];
    __shared__ float colred[4][64];
    u16* Al = (u16*)smraw;
    u16* Bl = (u16*)(smraw + 18432);
    float* red = (float*)smraw;
    int tid = threadIdx.x;
    int i0 = blockIdx.x * 128, j0 = blockIdx.y * 128;
    const uint4 zero4 = make_uint4(0, 0, 0, 0);
    for (int u = tid; u < 1024; u += 256) {
        int row = u >> 3, ch = u & 7;
        int ga = i0 + row, gb = j0 + row;
        uint4 va = (ga < PN) ? ((const uint4*)Ab)[(size_t)ga * 8 + ch] : zero4;
        uint4 vb = (gb < PN) ? ((const uint4*)Bb)[(size_t)gb * 8 + ch] : zero4;
        ((uint4*)Al)[row * 9 + ch] = va;
        ((uint4*)Bl)[row * 9 + ch] = vb;
    }
    __syncthreads();
    int wv = tid >> 6, lane = tid & 63;
    int wr = (wv & 1) * 64;
    int wc = (wv >> 1) * 64;
    int quad = lane >> 4, l15 = lane & 15;

    short8 af[4][2], bf[4][2];
#pragma unroll
    for (int t = 0; t < 4; t++)
#pragma unroll
        for (int ks = 0; ks < 2; ks++) {
            af[t][ks] = *(const short8*)&Al[(wr + t * 16 + l15) * 72 + ks * 32 + quad * 8];
            bf[t][ks] = *(const short8*)&Bl[(wc + t * 16 + l15) * 72 + ks * 32 + quad * 8];
        }
    __syncthreads();   // frags in regs; LDS (red) reusable after this

    f32x4 acc[4][4];
#pragma unroll
    for (int rt = 0; rt < 4; rt++)
#pragma unroll
        for (int ct = 0; ct < 4; ct++) {
            f32x4 c = {0.f, 0.f, 0.f, 0.f};
            c = __builtin_amdgcn_mfma_f32_16x16x32_bf16(af[rt][0], bf[ct][0], c, 0, 0, 0);
            c = __builtin_amdgcn_mfma_f32_16x16x32_bf16(af[rt][1], bf[ct][1], c, 0, 0, 0);
            acc[rt][ct] = c;
        }

    float rs[4][4];
#pragma unroll
    for (int rt = 0; rt < 4; rt++)
#pragma unroll
        for (int g = 0; g < 4; g++) rs[rt][g] = 0.f;
    float cs[4] = {0.f, 0.f, 0.f, 0.f};

    bool interior = (i0 + 128 <= PN) && (j0 + 128 <= PN) && (i0 != j0);
    if (interior) {
#pragma unroll
        for (int rt = 0; rt < 4; rt++)
#pragma unroll
            for (int ct = 0; ct < 4; ct++) {
                float csum = 0.f;
#pragma unroll
                for (int g = 0; g < 4; g++) {
                    float e = __builtin_amdgcn_exp2f(acc[rt][ct][g]);
                    rs[rt][g] += e;
                    csum += e;
                }
                cs[ct] += csum;
            }
    } else {
#pragma unroll
        for (int rt = 0; rt < 4; rt++) {
            int ibase = i0 + wr + rt * 16 + quad * 4;
#pragma unroll
            for (int ct = 0; ct < 4; ct++) {
                int j = j0 + wc + ct * 16 + l15;
                bool jv = (j < PN);
                float csum = 0.f;
#pragma unroll
                for (int g = 0; g < 4; g++) {
                    int i = ibase + g;
                    float e = 0.f;
                    if (jv && i < PN) {
                        e = __builtin_amdgcn_exp2f(acc[rt][ct][g]);
                        if (i == j) pos[i] = e;
                    }
                    rs[rt][g] += e;
                    csum += e;
                }
                cs[ct] += csum;
            }
        }
    }
    // col partial: reduce across quads (xor 16,32), stage per-wave (no race)
#pragma unroll
    for (int off = 16; off <= 32; off <<= 1)
#pragma unroll
        for (int ct = 0; ct < 4; ct++) cs[ct] += __shfl_xor(cs[ct], off, 64);
    if (quad == 0) {
#pragma unroll
        for (int ct = 0; ct < 4; ct++) colred[wv][ct * 16 + l15] = cs[ct];
    }
    // row partial: LDS transpose stage (unique (slot,rl) owner per thread)
    int slot = (wv >> 1) * 16 + l15;
#pragma unroll
    for (int rt = 0; rt < 4; rt++)
#pragma unroll
        for (int g = 0; g < 4; g++) {
            int rl = wr + rt * 16 + quad * 4 + g;
            red[slot * 131 + rl] = rs[rt][g];
        }
    __syncthreads();
    if (tid < 128) {
        // rowpart
        float sum = 0.f;
#pragma unroll
        for (int s2 = 0; s2 < 32; s2++) sum += red[s2 * 131 + tid];
        int i = i0 + tid;
        if (i < PN) rowpart[(size_t)blockIdx.y * PN + i] = sum;
        // colpart: combine wave pair (0+1 -> cols 0..63, 2+3 -> cols 64..127)
        int half = tid >> 6, jl = tid & 63;
        float cv = colred[half * 2 + 0][jl] + colred[half * 2 + 1][jl];
        int j = j0 + half * 64 + jl;
        if (j < PN) colpart[(size_t)blockIdx.x * PN + j] = cv;
    }
}

// reduce striped partials -> rowsum/colsum (coalesced column sums)
__global__ __launch_bounds__(256) void reduce_sums_kernel(
        const float* __restrict__ rowpart, const float* __restrict__ colpart,
        float* __restrict__ rowsum, float* __restrict__ colsum) {
    int t = blockIdx.x * 256 + threadIdx.x;
    if (t >= 2 * PN) return;
    const float* src; float* dst; int i;
    if (t < PN) { src = rowpart; dst = rowsum; i = t; }
    else        { src = colpart; dst = colsum; i = t - PN; }
    float s = 0.f;
    for (int w = 0; w < NSTR; w++) s += src[(size_t)w * PN + i];
    dst[i] = s;
}

// ====== batch: per-batch-row up-spmm (users_struct[idx[b]]) + norm + loss ======
__global__ void batch_spmm_loss_kernel(const int* __restrict__ rp, const int2* __restrict__ ent,
                                       const float* __restrict__ x, const int* __restrict__ idx,
                                       float* __restrict__ outb, const float* __restrict__ pos,
                                       const float* __restrict__ n1, const float* __restrict__ n2,
                                       float* __restrict__ outl) {
    __shared__ float red[256];
    int tid = threadIdx.x;
    if ((int)blockIdx.x < 1024) {
        int lane = tid & 63;
        int b = blockIdx.x * 4 + (tid >> 6);
        int r = idx[b];
        float v = spmm_row_acc(ent, x, rp[r], rp[r + 1], lane, 0.0f);
        float s = v * v;
#pragma unroll
        for (int off = 32; off > 0; off >>= 1) s += __shfl_xor(s, off, 64);
        float d = fmaxf(sqrtf(s), 1e-12f);
        outb[(size_t)b * 64 + lane] = v / d;
        return;
    }
    float acc = 0.0f;
    for (int i = tid; i < PN; i += 256) {
        float p = pos[i];
        acc += -logf(p / (n1[i] + 1e-8f) + 1e-8f);
        acc += -logf(p / (n2[i] + 1e-8f) + 1e-8f);
    }
    red[tid] = acc;
    __syncthreads();
    for (int s = 128; s > 0; s >>= 1) {
        if (tid < s) red[tid] += red[tid + s];
        __syncthreads();
    }
    if (tid == 0) outl[0] = 0.5f * red[0] / (float)PN;
}

extern "C" void kernel_launch(void* const* d_in, const int* in_sizes, int n_in,
                              void* d_out, int out_size, void* d_ws, size_t ws_size,
                              hipStream_t stream) {
    (void)in_sizes; (void)n_in; (void)out_size; (void)ws_size;
    const float* poi  = (const float*)d_in[0];
    const float* uemb = (const float*)d_in[1];
    const float* wgg  = (const float*)d_in[2];
    const float* bgg  = (const float*)d_in[3];
    const float* wgs  = (const float*)d_in[4];
    const float* bgs  = (const float*)d_in[5];
    const float* wgc  = (const float*)d_in[6];
    const float* bgc  = (const float*)d_in[7];
    const float* fw   = (const float*)d_in[8];
    const float* fb   = (const float*)d_in[9];
    const float* geo_vals = (const float*)d_in[10];
    const float* src_vals = (const float*)d_in[11];
    const float* tar_vals = (const float*)d_in[12];
    const float* up_vals  = (const float*)d_in[13];
    const float* pu_vals  = (const float*)d_in[14];
    const int* geo_rows = (const int*)d_in[15];
    const int* geo_cols = (const int*)d_in[16];
    const int* src_rows = (const int*)d_in[17];
    const int* src_cols = (const int*)d_in[18];
    const int* tar_rows = (const int*)d_in[19];
    const int* tar_cols = (const int*)d_in[20];
    const int* up_rows  = (const int*)d_in[21];
    const int* up_cols  = (const int*)d_in[22];
    const int* pu_rows  = (const int*)d_in[23];
    const int* pu_cols  = (const int*)d_in[24];
    const int* user_idx = (const int*)d_in[25];

    const int PD = PN * 64, UD = UN * 64;

    // ---- workspace layout (6 PD pools; ws is 256MiB, we use ~42MB)
    float* F = (float*)d_ws;
    float* rowsum = F;                  // PN
    float* colsum = rowsum + PN;        // PN
    float* pos    = colsum + PN;        // PN
    u16*   ngb    = (u16*)(F + 3 * PN); // PD bf16 (pre-scaled by SCALE_BF)
    u16*   nsb    = ngb + PD;           // PD bf16 (pre-scaled)
    float* U0     = F + 3 * PN + PD;    // UD
    float* P0     = U0 + UD;            // PD pools
    float* P1     = P0 + PD;
    float* P2     = P1 + PD;
    float* P3     = P2 + PD;
    float* P4     = P3 + PD;
    float* P5     = P4 + PD;

    // U0..P5 region time-shared: hist partials (1.68M ints) -> scatter temps
    // (1.76M int2 = 14.1MB <= 17.4MB) -> float pools
    int* part = (int*)U0;
    int2* tmp = (int2*)U0;
    int2* tmp_geo = tmp;
    int2* tmp_tar = tmp_geo + NGE;
    int2* tmp_src = tmp_tar + NDE;
    int2* tmp_up  = tmp_src + NDE;
    int2* tmp_pu  = tmp_up + NUE;

    int* M = (int*)(P5 + PD);           // CSR meta
    int* geo_rp = M;               int* geo_tot = geo_rp + PN + 1;
    int* tar_rp = geo_tot + PN;    int* tar_tot = tar_rp + PN + 1;
    int* src_rp = tar_tot + PN;    int* src_tot = src_rp + PN + 1;
    int* up_rp  = src_tot + PN;    int* up_tot  = up_rp + UN + 1;
    int* pu_rp  = up_tot + UN;     int* pu_tot  = pu_rp + PN + 1;
    int* bcur   = M + 96006;            // 640 bucket cursors
    const int meta_ints = 96646;        // even -> entries stay 8B-aligned
    int2* geo_ent = (int2*)(M + meta_ints);
    int2* tar_ent = geo_ent + NGE;
    int2* src_ent = tar_ent + NDE;
    int2* up_ent  = src_ent + NDE;
    int2* pu_ent  = up_ent + NUE;

    // infonce striped partials overlay the geo/tar/src entry region
    // (dead after step 8): 2 * 79 * PN floats = 6.32MB <= 7.68MB
    float* rowpart = (float*)geo_ent;
    float* colpart = rowpart + (size_t)NSTR * PN;

    float* out_bu = (float*)d_out;
    float* out_fp = out_bu + (size_t)BN * 64;
    float* out_loss = out_fp + (size_t)PN * 64;

    const int RB = PN / 4;     // 2500
    const int UB = UN / 4;     // 2000

    // 1. histogram via LDS partials (176 blocks)
    hist_lds_kernel<<<176, 256, 0, stream>>>(geo_rows, tar_rows, src_rows, up_rows, pu_rows, part);
    // 2a. sum partials per row (coalesced, 188 blocks)
    sum_partials_kernel<<<188, 256, 0, stream>>>(part, geo_tot, tar_tot, src_tot, up_tot, pu_tot);
    // 2b. LDS-staged exclusive scan -> rp + bucket cursors
    scan_lds_kernel<<<5, 1024, 0, stream>>>(geo_tot, tar_tot, src_tot, up_tot, pu_tot,
                                            geo_rp, tar_rp, src_rp, up_rp, pu_rp, bcur);
    // 3a. pass 1: bin into temp bucket regions (sequential-run writes)
    scatter_p1_kernel<<<NCT, 256, 0, stream>>>(
        geo_rows, geo_cols, geo_vals, tmp_geo,
        tar_rows, tar_cols, tar_vals, tmp_tar,
        src_rows, src_cols, src_vals, tmp_src,
        up_rows, up_cols, up_vals, tmp_up,
        pu_rows, pu_cols, pu_vals, tmp_pu,
        bcur);
    // 3b. pass 2: single-writer per-region scatter to final CSR entries
    scatter_p2_kernel<<<640, 256, 0, stream>>>(
        geo_rp, tmp_geo, geo_ent,
        tar_rp, tmp_tar, tar_ent,
        src_rp, tmp_src, src_ent,
        up_rp, tmp_up, up_ent,
        pu_rp, tmp_pu, pu_ent);
    // 4. gates: geo_g->P0, seq_g->P1, col_g->P2 (temp dead from here)
    gates3_kernel<<<RB, 256, 0, stream>>>(poi, wgg, bgg, wgs, bgs, wgc, bgc, P0, P1, P2);

    SpmmJob jz = {};
    // 5. dual: x1_g = A*geo_g + geo_g -> P3   ||   m1 = T*seq_g -> P4
    SpmmJob j_geo1 = {geo_rp, geo_ent, P0, P0, nullptr, nullptr, P3, nullptr, PN, 0};
    SpmmJob j_tar1 = {tar_rp, tar_ent, P1, nullptr, nullptr, nullptr, P4, nullptr, PN, 0};
    spmm_jobs_kernel<<<2 * RB, 256, 0, stream>>>(j_geo1, j_tar1, RB);
    // 6. dual (independent chains): geo-final ng -> P0  ||  x1_s = S*m1 + seq_g -> P5
    SpmmJob j_geo2 = {geo_rp, geo_ent, P3, P3, P0, P3, P0, ngb, PN, 1};
    SpmmJob j_s1   = {src_rp, src_ent, P4, P1, nullptr, nullptr, P5, nullptr, PN, 0};
    spmm_jobs_kernel<<<2 * RB, 256, 0, stream>>>(j_geo2, j_s1, RB);
    // 7. m2 = T*x1_s -> P4 (m1 dead)
    SpmmJob j_tar2 = {tar_rp, tar_ent, P5, nullptr, nullptr, nullptr, P4, nullptr, PN, 0};
    spmm_jobs_kernel<<<RB, 256, 0, stream>>>(j_tar2, jz, RB);
    // 8. ns-final: x2 = S*m2 + x1_s; ns = norm((seq_g+x1_s+x2)/3) -> P1
    SpmmJob j_s2 = {src_rp, src_ent, P4, P5, P1, P5, P1, nsb, PN, 1};
    spmm_jobs_kernel<<<RB, 256, 0, stream>>>(j_s2, jz, RB);
    // 9. InfoNCE (MFMA, striped partials; geo/tar/src entries dead from here)
    dim3 ig(NSTR, NSTR);
    infonce_mfma_kernel<<<ig, 256, 0, stream>>>(ngb, nsb, rowpart, colpart, pos);
    // 9b. reduce partials -> rowsum/colsum
    reduce_sums_kernel<<<(2 * PN + 255) / 256, 256, 0, stream>>>(rowpart, colpart, rowsum, colsum);
    // 10a+b. m_geo = up*ng -> P4 || m_seq = up*ns -> P3 (independent, dual dispatch)
    SpmmJob j_mg = {up_rp, up_ent, P0, nullptr, nullptr, nullptr, P4, nullptr, UN, 0};
    SpmmJob j_ms = {up_rp, up_ent, P1, nullptr, nullptr, nullptr, P3, nullptr, UN, 0};
    spmm_jobs_kernel<<<2 * UB, 256, 0, stream>>>(j_mg, j_ms, UB);
    // 10c. fuse (m_poi spmm inline, 2 rows/wave, 8 rows/block) -> U0
    fuse_users_spmm_kernel<<<UN / 8, 256, 0, stream>>>(up_rp, up_ent, P2, P4, P3, fw, fb, uemb, U0);
    // 11. hg_pois = col_g + pu*hg; fusion = norm + ng + ns -> P3 + out
    pu_out_kernel<<<RB, 256, 0, stream>>>(pu_rp, pu_ent, U0, P2, P0, P1, P3, out_fp);
    // 12. batch: per-row up-spmm of fusion + norm + loss
    batch_spmm_loss_kernel<<<1025, 256, 0, stream>>>(up_rp, up_ent, P3, user_idx,
                                                     out_bu, pos, rowsum, colsum, out_loss);
}